// Round 2
// baseline (1500.519 us; speedup 1.0000x reference)
//
#include <hip/hip_runtime.h>
#include <hip/hip_bf16.h>

// Decomposable attention, full bf16-MFMA pipeline, processed in two
// batch-halves (Bh=64) to keep workspace under ~175 MiB.

using f32x4 = __attribute__((ext_vector_type(4))) float;
using s16x8 = __attribute__((ext_vector_type(8))) short;

__device__ __forceinline__ void gload_lds16(const short* g, short* l) {
  __builtin_amdgcn_global_load_lds(
      (const __attribute__((address_space(1))) unsigned int*)g,
      (__attribute__((address_space(3))) unsigned int*)l, 16, 0, 0);
}

// ---------------- GEMM: C[M,N] = A[M,K] * B[N,K]^T (+bias, relu) ----------------
// grid = (N/128, M/128, batch), block = 256. K % 32 == 0, M,N multiples of 128.
template <bool RELU, bool OUT_BF16, bool HAS_BIAS>
__global__ __launch_bounds__(256) void gemm_nt(
    const short* __restrict__ A, const short* __restrict__ B,
    const float* __restrict__ bias, void* __restrict__ Cv, int K, int lda,
    int ldb, int ldc, long sA, long sB, long sC) {
  __shared__ __align__(16) short As[128 * 32];
  __shared__ __align__(16) short Bs[128 * 32];
  const int t = threadIdx.x;
  const int lane = t & 63;
  const int wave = t >> 6;
  const int m0 = blockIdx.y * 128;
  const int n0 = blockIdx.x * 128;
  const long zb = blockIdx.z;
  const short* Ab = A + zb * sA;
  const short* Bb = B + zb * sB;

  // staging: thread t loads 16B chunk (t&3) of row (t>>2); lands at LDS byte t*16
  const short* Ag = Ab + (long)(m0 + (t >> 2)) * lda + (t & 3) * 8;
  const short* Bg = Bb + (long)(n0 + (t >> 2)) * ldb + (t & 3) * 8;
  short* AsW = As + wave * 512;  // wave-uniform LDS base (bytes: wave*1024)
  short* BsW = Bs + wave * 512;

  const int fr = lane & 15;        // frag m/n index
  const int fk = (lane >> 4) * 8;  // frag k base
  int aoff[4], boff[4];
#pragma unroll
  for (int i = 0; i < 4; ++i) {
    aoff[i] = ((wave >> 1) * 64 + i * 16 + fr) * 32 + fk;
    boff[i] = ((wave & 1) * 64 + i * 16 + fr) * 32 + fk;
  }

  f32x4 acc[4][4] = {};

  for (int k0 = 0; k0 < K; k0 += 32) {
    gload_lds16(Ag + k0, AsW);
    gload_lds16(Ag + (long)64 * lda + k0, AsW + 2048);
    gload_lds16(Bg + k0, BsW);
    gload_lds16(Bg + (long)64 * ldb + k0, BsW + 2048);
    __syncthreads();  // compiler drains vmcnt before s_barrier
    s16x8 af[4], bfv[4];
#pragma unroll
    for (int i = 0; i < 4; ++i) af[i] = *(const s16x8*)(As + aoff[i]);
#pragma unroll
    for (int j = 0; j < 4; ++j) bfv[j] = *(const s16x8*)(Bs + boff[j]);
#pragma unroll
    for (int i = 0; i < 4; ++i)
#pragma unroll
      for (int j = 0; j < 4; ++j)
        acc[i][j] = __builtin_amdgcn_mfma_f32_16x16x32_bf16(af[i], bfv[j],
                                                            acc[i][j], 0, 0, 0);
    __syncthreads();
  }

  // C/D layout: col = lane&15, row = (lane>>4)*4 + reg  [m89/m91-verified]
  const int ccol = lane & 15;
  const int crow = (lane >> 4) * 4;
#pragma unroll
  for (int j = 0; j < 4; ++j) {
    const int col = n0 + (wave & 1) * 64 + j * 16 + ccol;
    float bj = 0.f;
    if (HAS_BIAS) bj = bias[col];
#pragma unroll
    for (int i = 0; i < 4; ++i) {
      const int row0 = m0 + (wave >> 1) * 64 + i * 16 + crow;
#pragma unroll
      for (int r = 0; r < 4; ++r) {
        float x = acc[i][j][r] + bj;
        if (RELU) x = fmaxf(x, 0.f);
        const long idx = (long)(row0 + r) * ldc + col + zb * sC;
        if (OUT_BF16)
          ((__hip_bfloat16*)Cv)[idx] = __float2bfloat16(x);
        else
          ((float*)Cv)[idx] = x;
      }
    }
  }
}

// ---------------- helpers ----------------
__global__ void cast_bf16(const float* __restrict__ in,
                          __hip_bfloat16* __restrict__ out, long n) {
  long i = ((long)blockIdx.x * blockDim.x + threadIdx.x) * 4;
  if (i >= n) return;
  float4 v = *(const float4*)(in + i);
  out[i + 0] = __float2bfloat16(v.x);
  out[i + 1] = __float2bfloat16(v.y);
  out[i + 2] = __float2bfloat16(v.z);
  out[i + 3] = __float2bfloat16(v.w);
}

// sent [Bh][L=256][E=512] f32 -> out [Bh][E][L] bf16
__global__ void transpose_cast(const float* __restrict__ in,
                               __hip_bfloat16* __restrict__ out) {
  __shared__ float tile[32][33];
  const int b = blockIdx.z;
  const int e0 = blockIdx.x * 32;
  const int l0 = blockIdx.y * 32;
  const float* ib = in + (long)b * 256 * 512;
  __hip_bfloat16* ob = out + (long)b * 256 * 512;
  const int tx = threadIdx.x, ty = threadIdx.y;
#pragma unroll
  for (int k = 0; k < 4; ++k)
    tile[ty + 8 * k][tx] = ib[(long)(l0 + ty + 8 * k) * 512 + e0 + tx];
  __syncthreads();
#pragma unroll
  for (int k = 0; k < 4; ++k)
    ob[(long)(e0 + ty + 8 * k) * 256 + l0 + tx] =
        __float2bfloat16(tile[tx][ty + 8 * k]);
}

// fill concat right half: out[row*1024 + 512 + c] = bf16(in[row*512+c])
__global__ void concat_fill(const float* __restrict__ in,
                            __hip_bfloat16* __restrict__ out) {
  const long i = (long)blockIdx.x * 256 + threadIdx.x;  // < 16384*512
  const long row = i >> 9;
  const int c = (int)(i & 511);
  out[row * 1024 + 512 + c] = __float2bfloat16(in[i]);
}

// row softmax over 256 cols: E fp32 [rows][256] -> W bf16
__global__ void softmax_rows(const float* __restrict__ E,
                             __hip_bfloat16* __restrict__ W) {
  const long row = blockIdx.x;
  const int t = threadIdx.x;
  const float x = E[row * 256 + t];
  float m = x;
  for (int o = 32; o > 0; o >>= 1) m = fmaxf(m, __shfl_xor(m, o));
  __shared__ float red[4];
  if ((t & 63) == 0) red[t >> 6] = m;
  __syncthreads();
  m = fmaxf(fmaxf(red[0], red[1]), fmaxf(red[2], red[3]));
  const float pr = __expf(x - m);
  float s = pr;
  for (int o = 32; o > 0; o >>= 1) s += __shfl_xor(s, o);
  __shared__ float red2[4];
  if ((t & 63) == 0) red2[t >> 6] = s;
  __syncthreads();
  s = red2[0] + red2[1] + red2[2] + red2[3];
  W[row * 256 + t] = __float2bfloat16(pr / s);
}

// col softmax: W[b][j][i] = softmax_i E[b][i][j]; grid (256 j, Bh b)
__global__ void softmax_cols(const float* __restrict__ E,
                             __hip_bfloat16* __restrict__ W) {
  const int j = blockIdx.x;
  const int b = blockIdx.y;
  const int t = threadIdx.x;  // = i
  const float x = E[(long)b * 65536 + (long)t * 256 + j];
  float m = x;
  for (int o = 32; o > 0; o >>= 1) m = fmaxf(m, __shfl_xor(m, o));
  __shared__ float red[4];
  if ((t & 63) == 0) red[t >> 6] = m;
  __syncthreads();
  m = fmaxf(fmaxf(red[0], red[1]), fmaxf(red[2], red[3]));
  const float pr = __expf(x - m);
  float s = pr;
  for (int o = 32; o > 0; o >>= 1) s += __shfl_xor(s, o);
  __shared__ float red2[4];
  if ((t & 63) == 0) red2[t >> 6] = s;
  __syncthreads();
  s = red2[0] + red2[1] + red2[2] + red2[3];
  W[(long)b * 65536 + (long)j * 256 + t] = __float2bfloat16(pr / s);
}

// s[b][h] = sum_i cmp[b*256+i][h]; write bf16 to scat[b*2048 + off + h]
__global__ void sum_l(const __hip_bfloat16* __restrict__ cmp,
                      __hip_bfloat16* __restrict__ scat, int off) {
  const int h = blockIdx.x * 256 + threadIdx.x;
  const int b = blockIdx.y;
  const __hip_bfloat16* q = cmp + (long)b * 256 * 1024 + h;
  float s = 0.f;
#pragma unroll 8
  for (int i = 0; i < 256; ++i) s += __bfloat162float(q[(long)i * 1024]);
  scat[(long)b * 2048 + off + h] = __float2bfloat16(s);
}

// out[b][o] = sum_h h2[b][h]*fin_w[o][h] + fin_b[o]
__global__ void final_lin(const __hip_bfloat16* __restrict__ h2,
                          const float* __restrict__ w,
                          const float* __restrict__ bs,
                          float* __restrict__ out) {
  const int b = blockIdx.x;
  const int t = threadIdx.x;
  float p0 = 0.f, p1 = 0.f, p2 = 0.f;
  for (int k = t; k < 1024; k += 256) {
    const float x = __bfloat162float(h2[(long)b * 1024 + k]);
    p0 += x * w[k];
    p1 += x * w[1024 + k];
    p2 += x * w[2048 + k];
  }
  for (int o = 32; o > 0; o >>= 1) {
    p0 += __shfl_xor(p0, o);
    p1 += __shfl_xor(p1, o);
    p2 += __shfl_xor(p2, o);
  }
  __shared__ float r[4][3];
  if ((t & 63) == 0) {
    r[t >> 6][0] = p0;
    r[t >> 6][1] = p1;
    r[t >> 6][2] = p2;
  }
  __syncthreads();
  if (t < 3)
    out[b * 3 + t] = r[0][t] + r[1][t] + r[2][t] + r[3][t] + bs[t];
}

extern "C" void kernel_launch(void* const* d_in, const int* in_sizes, int n_in,
                              void* d_out, int out_size, void* d_ws,
                              size_t ws_size, hipStream_t stream) {
  const float* sent1 = (const float*)d_in[0];
  const float* sent2 = (const float*)d_in[1];
  const float* f_w1 = (const float*)d_in[2];
  const float* f_b1 = (const float*)d_in[3];
  const float* f_w2 = (const float*)d_in[4];
  const float* f_b2 = (const float*)d_in[5];
  const float* g_w1 = (const float*)d_in[6];
  const float* g_b1 = (const float*)d_in[7];
  const float* g_w2 = (const float*)d_in[8];
  const float* g_b2 = (const float*)d_in[9];
  const float* h_w1 = (const float*)d_in[10];
  const float* h_b1 = (const float*)d_in[11];
  const float* h_w2 = (const float*)d_in[12];
  const float* h_b2 = (const float*)d_in[13];
  const float* fin_w = (const float*)d_in[14];
  const float* fin_b = (const float*)d_in[15];

  char* p = (char*)d_ws;
  auto take = [&](size_t n) {
    char* r = p;
    p += (n + 255) & ~(size_t)255;
    return r;
  };
  const size_t MB16 = 16777216;
  // weights (bf16)
  short* Wf1 = (short*)take(1024L * 512 * 2);
  short* Wf2 = (short*)take(1024L * 1024 * 2);
  short* Wg1 = (short*)take(1024L * 1024 * 2);
  short* Wg2 = (short*)take(1024L * 1024 * 2);
  short* Wh1 = (short*)take(1024L * 2048 * 2);
  short* Wh2 = (short*)take(1024L * 1024 * 2);
  short* scat = (short*)take(128L * 2048 * 2);
  short* hh = (short*)take(128L * 1024 * 2);
  short* hf = (short*)take(128L * 1024 * 2);
  // 10 x 16 MiB units, aliased per phase (per half-batch Bh=64):
  short* U1 = (short*)take(MB16);       // S1b [16384,512] bf16
  short* U2 = (short*)take(MB16);       // S2b
  short* U3 = (short*)take(2 * MB16);   // S1T | S2T  -> later cmp [16384,1024]
  short* U5 = (short*)take(2 * MB16);   // fhid [16384,1024] -> E1(fp32,16M)+W1A(8M)+W2A(8M) -> ghid
  short* U7 = (short*)take(2 * MB16);   // F1 [16384,1024] -> concat1
  short* U9 = (short*)take(2 * MB16);   // F2 -> concat2
  (void)ws_size; (void)in_sizes; (void)n_in; (void)out_size;

  short* S1T = U3;
  short* S2T = U3 + 8388608;           // +16 MiB (in shorts)
  short* CMP = U3;
  short* FHID = U5;
  float* E1 = (float*)U5;              // 16 MiB fp32
  short* W1A = U5 + 8388608;           // +16 MiB
  short* W2A = U5 + 12582912;          // +24 MiB
  short* GHID = U5;
  short* F1 = U7;
  short* CC1 = U7;
  short* F2 = U9;
  short* CC2 = U9;

  // ---- weight casts (once) ----
  cast_bf16<<<512, 256, 0, stream>>>(f_w1, (__hip_bfloat16*)Wf1, 524288);
  cast_bf16<<<1024, 256, 0, stream>>>(f_w2, (__hip_bfloat16*)Wf2, 1048576);
  cast_bf16<<<1024, 256, 0, stream>>>(g_w1, (__hip_bfloat16*)Wg1, 1048576);
  cast_bf16<<<1024, 256, 0, stream>>>(g_w2, (__hip_bfloat16*)Wg2, 1048576);
  cast_bf16<<<2048, 256, 0, stream>>>(h_w1, (__hip_bfloat16*)Wh1, 2097152);
  cast_bf16<<<1024, 256, 0, stream>>>(h_w2, (__hip_bfloat16*)Wh2, 1048576);

  for (int half = 0; half < 2; ++half) {
    const float* s1 = sent1 + (long)half * 16384 * 512;
    const float* s2 = sent2 + (long)half * 16384 * 512;
    short* scat_h = scat + (long)half * 64 * 2048;

    cast_bf16<<<8192, 256, 0, stream>>>(s1, (__hip_bfloat16*)U1, 8388608);
    cast_bf16<<<8192, 256, 0, stream>>>(s2, (__hip_bfloat16*)U2, 8388608);
    transpose_cast<<<dim3(16, 8, 64), dim3(32, 8), 0, stream>>>(
        s1, (__hip_bfloat16*)S1T);
    transpose_cast<<<dim3(16, 8, 64), dim3(32, 8), 0, stream>>>(
        s2, (__hip_bfloat16*)S2T);

    // ---- attend MLP f ----
    gemm_nt<true, true, true><<<dim3(8, 128, 1), 256, 0, stream>>>(
        U1, Wf1, f_b1, FHID, 512, 512, 512, 1024, 0, 0, 0);
    gemm_nt<true, true, true><<<dim3(8, 128, 1), 256, 0, stream>>>(
        FHID, Wf2, f_b2, F1, 1024, 1024, 1024, 1024, 0, 0, 0);
    gemm_nt<true, true, true><<<dim3(8, 128, 1), 256, 0, stream>>>(
        U2, Wf1, f_b1, FHID, 512, 512, 512, 1024, 0, 0, 0);
    gemm_nt<true, true, true><<<dim3(8, 128, 1), 256, 0, stream>>>(
        FHID, Wf2, f_b2, F2, 1024, 1024, 1024, 1024, 0, 0, 0);

    // ---- e1 = F1 F2^T (batched, fp32 out; overwrites FHID region) ----
    gemm_nt<false, false, false><<<dim3(2, 2, 64), 256, 0, stream>>>(
        F1, F2, nullptr, E1, 1024, 1024, 1024, 256, 256L * 1024, 256L * 1024,
        65536);

    // ---- softmaxes ----
    softmax_rows<<<16384, 256, 0, stream>>>(E1, (__hip_bfloat16*)W1A);
    softmax_cols<<<dim3(256, 64), 256, 0, stream>>>(E1, (__hip_bfloat16*)W2A);

    // ---- att into concat buffers (CC1 = [att1|sent1], CC2 = [att2|sent2]) ----
    gemm_nt<false, true, false><<<dim3(4, 2, 64), 256, 0, stream>>>(
        W1A, S2T, nullptr, CC1, 256, 256, 256, 1024, 65536, 131072, 262144);
    concat_fill<<<32768, 256, 0, stream>>>(s1, (__hip_bfloat16*)CC1);
    gemm_nt<false, true, false><<<dim3(4, 2, 64), 256, 0, stream>>>(
        W2A, S1T, nullptr, CC2, 256, 256, 256, 1024, 65536, 131072, 262144);
    concat_fill<<<32768, 256, 0, stream>>>(s2, (__hip_bfloat16*)CC2);

    // ---- compare MLP g + sum over L ----
    gemm_nt<true, true, true><<<dim3(8, 128, 1), 256, 0, stream>>>(
        CC1, Wg1, g_b1, GHID, 1024, 1024, 1024, 1024, 0, 0, 0);
    gemm_nt<true, true, true><<<dim3(8, 128, 1), 256, 0, stream>>>(
        GHID, Wg2, g_b2, CMP, 1024, 1024, 1024, 1024, 0, 0, 0);
    sum_l<<<dim3(4, 64), 256, 0, stream>>>((__hip_bfloat16*)CMP,
                                           (__hip_bfloat16*)scat_h, 0);
    gemm_nt<true, true, true><<<dim3(8, 128, 1), 256, 0, stream>>>(
        CC2, Wg1, g_b1, GHID, 1024, 1024, 1024, 1024, 0, 0, 0);
    gemm_nt<true, true, true><<<dim3(8, 128, 1), 256, 0, stream>>>(
        GHID, Wg2, g_b2, CMP, 1024, 1024, 1024, 1024, 0, 0, 0);
    sum_l<<<dim3(4, 64), 256, 0, stream>>>((__hip_bfloat16*)CMP,
                                           (__hip_bfloat16*)scat_h, 1024);
  }

  // ---- aggregate MLP h + final linear ----
  gemm_nt<true, true, true><<<dim3(8, 1, 1), 256, 0, stream>>>(
      scat, Wh1, h_b1, hh, 2048, 2048, 2048, 1024, 0, 0, 0);
  gemm_nt<true, true, true><<<dim3(8, 1, 1), 256, 0, stream>>>(
      hh, Wh2, h_b2, hf, 1024, 1024, 1024, 1024, 0, 0, 0);
  final_lin<<<128, 256, 0, stream>>>((__hip_bfloat16*)hf, fin_w, fin_b,
                                     (float*)d_out);
}

// Round 3
// 1349.373 us; speedup vs baseline: 1.1120x; 1.1120x over previous
//
#include <hip/hip_runtime.h>
#include <hip/hip_bf16.h>

// Decomposable attention, bf16-MFMA pipeline, two batch-halves (Bh=64).
// R3: XCD-aware block swizzle in gemm_nt; sum-over-L fused into GEMM epilogue;
// coalesced two-pass column softmax.

using f32x4 = __attribute__((ext_vector_type(4))) float;
using s16x8 = __attribute__((ext_vector_type(8))) short;

__device__ __forceinline__ void gload_lds16(const short* g, short* l) {
  __builtin_amdgcn_global_load_lds(
      (const __attribute__((address_space(1))) unsigned int*)g,
      (__attribute__((address_space(3))) unsigned int*)l, 16, 0, 0);
}

// ---------------- GEMM: C[M,N] = A[M,K] * B[N,K]^T (+bias, relu) ----------------
// grid = (N/128, M/128, batch), block = 256.
// SUML: instead of storing C, accumulate sum over rows (per 256-row batch)
// into float Cv[(m0>>8)*ldc + n0+col] via LDS-reduced global atomics.
template <bool RELU, bool OUT_BF16, bool HAS_BIAS, bool SUML>
__global__ __launch_bounds__(256) void gemm_nt(
    const short* __restrict__ A, const short* __restrict__ B,
    const float* __restrict__ bias, void* __restrict__ Cv, int K, int lda,
    int ldb, int ldc, long sA, long sB, long sC) {
  __shared__ __align__(16) short As[128 * 32];
  __shared__ __align__(16) short Bs[128 * 32];
  const int t = threadIdx.x;
  const int lane = t & 63;
  const int wave = t >> 6;

  // XCD-aware swizzle: flat%8 ~ XCD; give each XCD a contiguous flat range
  // (y-stripe, x-fastest) so blocks sharing an A-tile hit the same L2.
  unsigned flat = (blockIdx.z * gridDim.y + blockIdx.y) * gridDim.x + blockIdx.x;
  const unsigned total = gridDim.x * gridDim.y * gridDim.z;
  unsigned bx = blockIdx.x, by = blockIdx.y, bz = blockIdx.z;
  if ((total & 7u) == 0) {
    unsigned nf = (flat & 7u) * (total >> 3) + (flat >> 3);
    bx = nf % gridDim.x;
    unsigned rest = nf / gridDim.x;
    by = rest % gridDim.y;
    bz = rest / gridDim.y;
  }
  const int m0 = by * 128;
  const int n0 = bx * 128;
  const long zb = bz;
  const short* Ab = A + zb * sA;
  const short* Bb = B + zb * sB;

  // staging: thread t loads 16B chunk (t&3) of row (t>>2); lands at LDS byte t*16
  const short* Ag = Ab + (long)(m0 + (t >> 2)) * lda + (t & 3) * 8;
  const short* Bg = Bb + (long)(n0 + (t >> 2)) * ldb + (t & 3) * 8;
  short* AsW = As + wave * 512;  // wave-uniform LDS base (bytes: wave*1024)
  short* BsW = Bs + wave * 512;

  const int fr = lane & 15;        // frag m/n index
  const int fk = (lane >> 4) * 8;  // frag k base
  int aoff[4], boff[4];
#pragma unroll
  for (int i = 0; i < 4; ++i) {
    aoff[i] = ((wave >> 1) * 64 + i * 16 + fr) * 32 + fk;
    boff[i] = ((wave & 1) * 64 + i * 16 + fr) * 32 + fk;
  }

  f32x4 acc[4][4] = {};

  for (int k0 = 0; k0 < K; k0 += 32) {
    gload_lds16(Ag + k0, AsW);
    gload_lds16(Ag + (long)64 * lda + k0, AsW + 2048);
    gload_lds16(Bg + k0, BsW);
    gload_lds16(Bg + (long)64 * ldb + k0, BsW + 2048);
    __syncthreads();
    s16x8 af[4], bfv[4];
#pragma unroll
    for (int i = 0; i < 4; ++i) af[i] = *(const s16x8*)(As + aoff[i]);
#pragma unroll
    for (int j = 0; j < 4; ++j) bfv[j] = *(const s16x8*)(Bs + boff[j]);
#pragma unroll
    for (int i = 0; i < 4; ++i)
#pragma unroll
      for (int j = 0; j < 4; ++j)
        acc[i][j] = __builtin_amdgcn_mfma_f32_16x16x32_bf16(af[i], bfv[j],
                                                            acc[i][j], 0, 0, 0);
    __syncthreads();
  }

  // C/D layout: col = lane&15, row = (lane>>4)*4 + reg  [m89/m91-verified]
  const int ccol = lane & 15;
  const int crow = (lane >> 4) * 4;

  if constexpr (SUML) {
    __shared__ float ssum[128];
    if (t < 128) ssum[t] = 0.f;
    __syncthreads();
#pragma unroll
    for (int j = 0; j < 4; ++j) {
      const int lcol = (wave & 1) * 64 + j * 16 + ccol;
      float bj = HAS_BIAS ? bias[n0 + lcol] : 0.f;
      float part = 0.f;
#pragma unroll
      for (int i = 0; i < 4; ++i)
#pragma unroll
        for (int r = 0; r < 4; ++r) {
          float x = acc[i][j][r] + bj;
          if (RELU) x = fmaxf(x, 0.f);
          part += x;
        }
      atomicAdd(&ssum[lcol], part);
    }
    __syncthreads();
    if (t < 128)
      atomicAdd((float*)Cv + (long)(m0 >> 8) * ldc + n0 + t, ssum[t]);
  } else {
#pragma unroll
    for (int j = 0; j < 4; ++j) {
      const int col = n0 + (wave & 1) * 64 + j * 16 + ccol;
      float bj = 0.f;
      if (HAS_BIAS) bj = bias[col];
#pragma unroll
      for (int i = 0; i < 4; ++i) {
        const int row0 = m0 + (wave >> 1) * 64 + i * 16 + crow;
#pragma unroll
        for (int r = 0; r < 4; ++r) {
          float x = acc[i][j][r] + bj;
          if (RELU) x = fmaxf(x, 0.f);
          const long idx = (long)(row0 + r) * ldc + col + zb * sC;
          if (OUT_BF16)
            ((__hip_bfloat16*)Cv)[idx] = __float2bfloat16(x);
          else
            ((float*)Cv)[idx] = x;
        }
      }
    }
  }
}

// ---------------- helpers ----------------
__global__ void cast_bf16(const float* __restrict__ in,
                          __hip_bfloat16* __restrict__ out, long n) {
  long i = ((long)blockIdx.x * blockDim.x + threadIdx.x) * 4;
  if (i >= n) return;
  float4 v = *(const float4*)(in + i);
  out[i + 0] = __float2bfloat16(v.x);
  out[i + 1] = __float2bfloat16(v.y);
  out[i + 2] = __float2bfloat16(v.z);
  out[i + 3] = __float2bfloat16(v.w);
}

// sent [Bh][L=256][E=512] f32 -> out [Bh][E][L] bf16
__global__ void transpose_cast(const float* __restrict__ in,
                               __hip_bfloat16* __restrict__ out) {
  __shared__ float tile[32][33];
  const int b = blockIdx.z;
  const int e0 = blockIdx.x * 32;
  const int l0 = blockIdx.y * 32;
  const float* ib = in + (long)b * 256 * 512;
  __hip_bfloat16* ob = out + (long)b * 256 * 512;
  const int tx = threadIdx.x, ty = threadIdx.y;
#pragma unroll
  for (int k = 0; k < 4; ++k)
    tile[ty + 8 * k][tx] = ib[(long)(l0 + ty + 8 * k) * 512 + e0 + tx];
  __syncthreads();
#pragma unroll
  for (int k = 0; k < 4; ++k)
    ob[(long)(e0 + ty + 8 * k) * 256 + l0 + tx] =
        __float2bfloat16(tile[tx][ty + 8 * k]);
}

// fill concat right half: out[row*1024 + 512 + c] = bf16(in[row*512+c])
__global__ void concat_fill(const float* __restrict__ in,
                            __hip_bfloat16* __restrict__ out) {
  const long i = (long)blockIdx.x * 256 + threadIdx.x;  // < 16384*512
  const long row = i >> 9;
  const int c = (int)(i & 511);
  out[row * 1024 + 512 + c] = __float2bfloat16(in[i]);
}

// row softmax over 256 cols: E fp32 [rows][256] -> W bf16 (coalesced)
__global__ void softmax_rows(const float* __restrict__ E,
                             __hip_bfloat16* __restrict__ W) {
  const long row = blockIdx.x;
  const int t = threadIdx.x;
  const float x = E[row * 256 + t];
  float m = x;
  for (int o = 32; o > 0; o >>= 1) m = fmaxf(m, __shfl_xor(m, o));
  __shared__ float red[4];
  if ((t & 63) == 0) red[t >> 6] = m;
  __syncthreads();
  m = fmaxf(fmaxf(red[0], red[1]), fmaxf(red[2], red[3]));
  const float pr = __expf(x - m);
  float s = pr;
  for (int o = 32; o > 0; o >>= 1) s += __shfl_xor(s, o);
  __shared__ float red2[4];
  if ((t & 63) == 0) red2[t >> 6] = s;
  __syncthreads();
  s = red2[0] + red2[1] + red2[2] + red2[3];
  W[row * 256 + t] = __float2bfloat16(pr / s);
}

// column softmax pass 1: per (b, j) max & inv-sum over i. grid (4, Bh).
__global__ __launch_bounds__(256) void col_stats(const float* __restrict__ E,
                                                 float* __restrict__ Mb,
                                                 float* __restrict__ Sb) {
  const int b = blockIdx.y;
  const int j0 = blockIdx.x * 64;
  const int jl = threadIdx.x & 63, s = threadIdx.x >> 6;  // s in 0..3
  const float* Eb = E + (long)b * 65536 + j0 + jl;
  float m = -3.4e38f;
  for (int r = 0; r < 64; ++r) m = fmaxf(m, Eb[(long)(s * 64 + r) * 256]);
  __shared__ float mr[4][64], sr[4][64];
  mr[s][jl] = m;
  __syncthreads();
  m = fmaxf(fmaxf(mr[0][jl], mr[1][jl]), fmaxf(mr[2][jl], mr[3][jl]));
  float sum = 0.f;
  for (int r = 0; r < 64; ++r) sum += __expf(Eb[(long)(s * 64 + r) * 256] - m);
  sr[s][jl] = sum;
  __syncthreads();
  if (s == 0) {
    sum = sr[0][jl] + sr[1][jl] + sr[2][jl] + sr[3][jl];
    Mb[b * 256 + j0 + jl] = m;
    Sb[b * 256 + j0 + jl] = 1.0f / sum;
  }
}

// column softmax pass 2: W[b][j][i] = exp(E[b][i][j]-M[j])*invS[j], via 64x64
// LDS tile transpose; fully coalesced both sides. grid (4 i, 4 j, Bh).
__global__ __launch_bounds__(256) void softmax_cols_t(
    const float* __restrict__ E, const float* __restrict__ Mb,
    const float* __restrict__ Sb, __hip_bfloat16* __restrict__ W) {
  __shared__ float tile[64][65];
  const int b = blockIdx.z;
  const int i0 = blockIdx.x * 64;
  const int j0 = blockIdx.y * 64;
  const float* Eb = E + (long)b * 65536;
  const int tx = threadIdx.x & 63, ty = threadIdx.x >> 6;  // 64 x 4
#pragma unroll
  for (int k = 0; k < 16; ++k) {
    const int r = k * 4 + ty;
    tile[r][tx] = Eb[(long)(i0 + r) * 256 + j0 + tx];
  }
  __syncthreads();
#pragma unroll
  for (int k = 0; k < 16; ++k) {
    const int j = j0 + k * 4 + ty;
    const float mj = Mb[b * 256 + j];
    const float sj = Sb[b * 256 + j];
    const float v = __expf(tile[tx][k * 4 + ty] - mj) * sj;
    W[(long)b * 65536 + (long)j * 256 + i0 + tx] = __float2bfloat16(v);
  }
}

// out[b][o] = sum_h h2[b][h]*fin_w[o][h] + fin_b[o]
__global__ void final_lin(const __hip_bfloat16* __restrict__ h2,
                          const float* __restrict__ w,
                          const float* __restrict__ bs,
                          float* __restrict__ out) {
  const int b = blockIdx.x;
  const int t = threadIdx.x;
  float p0 = 0.f, p1 = 0.f, p2 = 0.f;
  for (int k = t; k < 1024; k += 256) {
    const float x = __bfloat162float(h2[(long)b * 1024 + k]);
    p0 += x * w[k];
    p1 += x * w[1024 + k];
    p2 += x * w[2048 + k];
  }
  for (int o = 32; o > 0; o >>= 1) {
    p0 += __shfl_xor(p0, o);
    p1 += __shfl_xor(p1, o);
    p2 += __shfl_xor(p2, o);
  }
  __shared__ float r[4][3];
  if ((t & 63) == 0) {
    r[t >> 6][0] = p0;
    r[t >> 6][1] = p1;
    r[t >> 6][2] = p2;
  }
  __syncthreads();
  if (t < 3)
    out[b * 3 + t] = r[0][t] + r[1][t] + r[2][t] + r[3][t] + bs[t];
}

extern "C" void kernel_launch(void* const* d_in, const int* in_sizes, int n_in,
                              void* d_out, int out_size, void* d_ws,
                              size_t ws_size, hipStream_t stream) {
  const float* sent1 = (const float*)d_in[0];
  const float* sent2 = (const float*)d_in[1];
  const float* f_w1 = (const float*)d_in[2];
  const float* f_b1 = (const float*)d_in[3];
  const float* f_w2 = (const float*)d_in[4];
  const float* f_b2 = (const float*)d_in[5];
  const float* g_w1 = (const float*)d_in[6];
  const float* g_b1 = (const float*)d_in[7];
  const float* g_w2 = (const float*)d_in[8];
  const float* g_b2 = (const float*)d_in[9];
  const float* h_w1 = (const float*)d_in[10];
  const float* h_b1 = (const float*)d_in[11];
  const float* h_w2 = (const float*)d_in[12];
  const float* h_b2 = (const float*)d_in[13];
  const float* fin_w = (const float*)d_in[14];
  const float* fin_b = (const float*)d_in[15];

  char* p = (char*)d_ws;
  auto take = [&](size_t n) {
    char* r = p;
    p += (n + 255) & ~(size_t)255;
    return r;
  };
  const size_t MB16 = 16777216;
  // weights (bf16)
  short* Wf1 = (short*)take(1024L * 512 * 2);
  short* Wf2 = (short*)take(1024L * 1024 * 2);
  short* Wg1 = (short*)take(1024L * 1024 * 2);
  short* Wg2 = (short*)take(1024L * 1024 * 2);
  short* Wh1 = (short*)take(1024L * 2048 * 2);
  short* Wh2 = (short*)take(1024L * 1024 * 2);
  float* SUMF = (float*)take(128L * 2048 * 4);  // fp32 sum-over-L accumulator
  short* scat = (short*)take(128L * 2048 * 2);
  short* hh = (short*)take(128L * 1024 * 2);
  short* hf = (short*)take(128L * 1024 * 2);
  float* Mb = (float*)take(64L * 256 * 4);
  float* Sb = (float*)take(64L * 256 * 4);
  // 16 MiB units, aliased per phase (per half-batch Bh=64):
  short* U1 = (short*)take(MB16);      // S1b [16384,512] bf16
  short* U2 = (short*)take(MB16);      // S2b
  short* U3 = (short*)take(2 * MB16);  // S1T | S2T
  short* U5 = (short*)take(2 * MB16);  // fhid -> E1(fp32)+W1A+W2A -> ghid
  short* U7 = (short*)take(2 * MB16);  // F1 -> concat1
  short* U9 = (short*)take(2 * MB16);  // F2 -> concat2
  (void)ws_size; (void)in_sizes; (void)n_in; (void)out_size;

  short* S1T = U3;
  short* S2T = U3 + 8388608;
  short* FHID = U5;
  float* E1 = (float*)U5;       // 16 MiB fp32
  short* W1A = U5 + 8388608;    // +16 MiB
  short* W2A = U5 + 12582912;   // +24 MiB
  short* GHID = U5;
  short* F1 = U7;
  short* CC1 = U7;
  short* F2 = U9;
  short* CC2 = U9;

  hipMemsetAsync(SUMF, 0, 128L * 2048 * 4, stream);

  // ---- weight casts (once) ----
  cast_bf16<<<512, 256, 0, stream>>>(f_w1, (__hip_bfloat16*)Wf1, 524288);
  cast_bf16<<<1024, 256, 0, stream>>>(f_w2, (__hip_bfloat16*)Wf2, 1048576);
  cast_bf16<<<1024, 256, 0, stream>>>(g_w1, (__hip_bfloat16*)Wg1, 1048576);
  cast_bf16<<<1024, 256, 0, stream>>>(g_w2, (__hip_bfloat16*)Wg2, 1048576);
  cast_bf16<<<2048, 256, 0, stream>>>(h_w1, (__hip_bfloat16*)Wh1, 2097152);
  cast_bf16<<<1024, 256, 0, stream>>>(h_w2, (__hip_bfloat16*)Wh2, 1048576);

  for (int half = 0; half < 2; ++half) {
    const float* s1 = sent1 + (long)half * 16384 * 512;
    const float* s2 = sent2 + (long)half * 16384 * 512;
    float* SUMF_h = SUMF + (long)half * 64 * 2048;

    cast_bf16<<<8192, 256, 0, stream>>>(s1, (__hip_bfloat16*)U1, 8388608);
    cast_bf16<<<8192, 256, 0, stream>>>(s2, (__hip_bfloat16*)U2, 8388608);
    transpose_cast<<<dim3(16, 8, 64), dim3(32, 8), 0, stream>>>(
        s1, (__hip_bfloat16*)S1T);
    transpose_cast<<<dim3(16, 8, 64), dim3(32, 8), 0, stream>>>(
        s2, (__hip_bfloat16*)S2T);

    // ---- attend MLP f ----
    gemm_nt<true, true, true, false><<<dim3(8, 128, 1), 256, 0, stream>>>(
        U1, Wf1, f_b1, FHID, 512, 512, 512, 1024, 0, 0, 0);
    gemm_nt<true, true, true, false><<<dim3(8, 128, 1), 256, 0, stream>>>(
        FHID, Wf2, f_b2, F1, 1024, 1024, 1024, 1024, 0, 0, 0);
    gemm_nt<true, true, true, false><<<dim3(8, 128, 1), 256, 0, stream>>>(
        U2, Wf1, f_b1, FHID, 512, 512, 512, 1024, 0, 0, 0);
    gemm_nt<true, true, true, false><<<dim3(8, 128, 1), 256, 0, stream>>>(
        FHID, Wf2, f_b2, F2, 1024, 1024, 1024, 1024, 0, 0, 0);

    // ---- e1 = F1 F2^T (batched, fp32 out; overwrites FHID region) ----
    gemm_nt<false, false, false, false><<<dim3(2, 2, 64), 256, 0, stream>>>(
        F1, F2, nullptr, E1, 1024, 1024, 1024, 256, 256L * 1024, 256L * 1024,
        65536);

    // ---- softmaxes ----
    softmax_rows<<<16384, 256, 0, stream>>>(E1, (__hip_bfloat16*)W1A);
    col_stats<<<dim3(4, 64), 256, 0, stream>>>(E1, Mb, Sb);
    softmax_cols_t<<<dim3(4, 4, 64), 256, 0, stream>>>(E1, Mb, Sb,
                                                       (__hip_bfloat16*)W2A);

    // ---- att into concat buffers (CC1 = [att1|sent1], CC2 = [att2|sent2]) ----
    gemm_nt<false, true, false, false><<<dim3(4, 2, 64), 256, 0, stream>>>(
        W1A, S2T, nullptr, CC1, 256, 256, 256, 1024, 65536, 131072, 262144);
    concat_fill<<<32768, 256, 0, stream>>>(s1, (__hip_bfloat16*)CC1);
    gemm_nt<false, true, false, false><<<dim3(4, 2, 64), 256, 0, stream>>>(
        W2A, S1T, nullptr, CC2, 256, 256, 256, 1024, 65536, 131072, 262144);
    concat_fill<<<32768, 256, 0, stream>>>(s2, (__hip_bfloat16*)CC2);

    // ---- compare MLP g; layer2 accumulates sum-over-L directly ----
    gemm_nt<true, true, true, false><<<dim3(8, 128, 1), 256, 0, stream>>>(
        CC1, Wg1, g_b1, GHID, 1024, 1024, 1024, 1024, 0, 0, 0);
    gemm_nt<true, false, true, true><<<dim3(8, 128, 1), 256, 0, stream>>>(
        GHID, Wg2, g_b2, SUMF_h, 1024, 1024, 1024, 2048, 0, 0, 0);
    gemm_nt<true, true, true, false><<<dim3(8, 128, 1), 256, 0, stream>>>(
        CC2, Wg1, g_b1, GHID, 1024, 1024, 1024, 1024, 0, 0, 0);
    gemm_nt<true, false, true, true><<<dim3(8, 128, 1), 256, 0, stream>>>(
        GHID, Wg2, g_b2, SUMF_h + 1024, 1024, 1024, 1024, 2048, 0, 0, 0);
  }

  // ---- aggregate MLP h + final linear ----
  cast_bf16<<<256, 256, 0, stream>>>(SUMF, (__hip_bfloat16*)scat, 262144);
  gemm_nt<true, true, true, false><<<dim3(8, 1, 1), 256, 0, stream>>>(
      scat, Wh1, h_b1, hh, 2048, 2048, 2048, 1024, 0, 0, 0);
  gemm_nt<true, true, true, false><<<dim3(8, 1, 1), 256, 0, stream>>>(
      hh, Wh2, h_b2, hf, 1024, 1024, 1024, 1024, 0, 0, 0);
  final_lin<<<128, 256, 0, stream>>>((__hip_bfloat16*)hf, fin_w, fin_b,
                                     (float*)d_out);
}

// Round 4
// 1237.453 us; speedup vs baseline: 1.2126x; 1.0904x over previous
//
#include <hip/hip_runtime.h>
#include <hip/hip_bf16.h>

// Decomposable attention, bf16-MFMA pipeline.
// R4: merge sent1/sent2 sides into single M=2*R GEMMs (R=Bh*256 rows/side) to
// double resident blocks/CU (latency-bound fix); chunk count gated on ws_size.

using f32x4 = __attribute__((ext_vector_type(4))) float;
using s16x8 = __attribute__((ext_vector_type(8))) short;

__device__ __forceinline__ void gload_lds16(const short* g, short* l) {
  __builtin_amdgcn_global_load_lds(
      (const __attribute__((address_space(1))) unsigned int*)g,
      (__attribute__((address_space(3))) unsigned int*)l, 16, 0, 0);
}

// ---------------- GEMM: C[M,N] = A[M,K] * B[N,K]^T (+bias, relu) ----------------
// grid = (N/128, M/128, batch), block = 256.
// SUML: accumulate sum over rows per 256-row batch into float Cv. Row-batches
// [0,split) are "side 1" -> cols [0,ldc/2); [split,2*split) are side 2 ->
// cols [ldc/2,ldc). sC carries `split`.
template <bool RELU, bool OUT_BF16, bool HAS_BIAS, bool SUML>
__global__ __launch_bounds__(256) void gemm_nt(
    const short* __restrict__ A, const short* __restrict__ B,
    const float* __restrict__ bias, void* __restrict__ Cv, int K, int lda,
    int ldb, int ldc, long sA, long sB, long sC) {
  __shared__ __align__(16) short As[128 * 32];
  __shared__ __align__(16) short Bs[128 * 32];
  const int t = threadIdx.x;
  const int lane = t & 63;
  const int wave = t >> 6;

  // XCD-aware swizzle: hw xcd ~ flat%8; give each XCD a contiguous tile range
  // (y-stripe, x-fastest) so blocks sharing an A-tile hit the same L2.
  unsigned flat = (blockIdx.z * gridDim.y + blockIdx.y) * gridDim.x + blockIdx.x;
  const unsigned total = gridDim.x * gridDim.y * gridDim.z;
  unsigned bx = blockIdx.x, by = blockIdx.y, bz = blockIdx.z;
  if ((total & 7u) == 0) {
    unsigned nf = (flat & 7u) * (total >> 3) + (flat >> 3);
    bx = nf % gridDim.x;
    unsigned rest = nf / gridDim.x;
    by = rest % gridDim.y;
    bz = rest / gridDim.y;
  }
  const int m0 = by * 128;
  const int n0 = bx * 128;
  const long zb = bz;
  const short* Ab = A + zb * sA;
  const short* Bb = B + zb * sB;

  const short* Ag = Ab + (long)(m0 + (t >> 2)) * lda + (t & 3) * 8;
  const short* Bg = Bb + (long)(n0 + (t >> 2)) * ldb + (t & 3) * 8;
  short* AsW = As + wave * 512;
  short* BsW = Bs + wave * 512;

  const int fr = lane & 15;
  const int fk = (lane >> 4) * 8;
  int aoff[4], boff[4];
#pragma unroll
  for (int i = 0; i < 4; ++i) {
    aoff[i] = ((wave >> 1) * 64 + i * 16 + fr) * 32 + fk;
    boff[i] = ((wave & 1) * 64 + i * 16 + fr) * 32 + fk;
  }

  f32x4 acc[4][4] = {};

  for (int k0 = 0; k0 < K; k0 += 32) {
    gload_lds16(Ag + k0, AsW);
    gload_lds16(Ag + (long)64 * lda + k0, AsW + 2048);
    gload_lds16(Bg + k0, BsW);
    gload_lds16(Bg + (long)64 * ldb + k0, BsW + 2048);
    __syncthreads();
    s16x8 af[4], bfv[4];
#pragma unroll
    for (int i = 0; i < 4; ++i) af[i] = *(const s16x8*)(As + aoff[i]);
#pragma unroll
    for (int j = 0; j < 4; ++j) bfv[j] = *(const s16x8*)(Bs + boff[j]);
#pragma unroll
    for (int i = 0; i < 4; ++i)
#pragma unroll
      for (int j = 0; j < 4; ++j)
        acc[i][j] = __builtin_amdgcn_mfma_f32_16x16x32_bf16(af[i], bfv[j],
                                                            acc[i][j], 0, 0, 0);
    __syncthreads();
  }

  // C/D layout: col = lane&15, row = (lane>>4)*4 + reg  [m89/m91-verified]
  const int ccol = lane & 15;
  const int crow = (lane >> 4) * 4;

  if constexpr (SUML) {
    __shared__ float ssum[128];
    if (t < 128) ssum[t] = 0.f;
    __syncthreads();
#pragma unroll
    for (int j = 0; j < 4; ++j) {
      const int lcol = (wave & 1) * 64 + j * 16 + ccol;
      float bj = HAS_BIAS ? bias[n0 + lcol] : 0.f;
      float part = 0.f;
#pragma unroll
      for (int i = 0; i < 4; ++i)
#pragma unroll
        for (int r = 0; r < 4; ++r) {
          float x = acc[i][j][r] + bj;
          if (RELU) x = fmaxf(x, 0.f);
          part += x;
        }
      atomicAdd(&ssum[lcol], part);
    }
    __syncthreads();
    if (t < 128) {
      const int split = (int)sC;
      int rb = m0 >> 8;
      const int side = rb >= split;
      rb -= side * split;
      atomicAdd((float*)Cv + (long)rb * ldc + side * (ldc >> 1) + n0 + t,
                ssum[t]);
    }
  } else {
#pragma unroll
    for (int j = 0; j < 4; ++j) {
      const int col = n0 + (wave & 1) * 64 + j * 16 + ccol;
      float bj = 0.f;
      if (HAS_BIAS) bj = bias[col];
#pragma unroll
      for (int i = 0; i < 4; ++i) {
        const int row0 = m0 + (wave >> 1) * 64 + i * 16 + crow;
#pragma unroll
        for (int r = 0; r < 4; ++r) {
          float x = acc[i][j][r] + bj;
          if (RELU) x = fmaxf(x, 0.f);
          const long idx = (long)(row0 + r) * ldc + col + zb * sC;
          if (OUT_BF16)
            ((__hip_bfloat16*)Cv)[idx] = __float2bfloat16(x);
          else
            ((float*)Cv)[idx] = x;
        }
      }
    }
  }
}

// ---------------- helpers ----------------
__global__ void cast_bf16(const float* __restrict__ in,
                          __hip_bfloat16* __restrict__ out, long n) {
  long i = ((long)blockIdx.x * blockDim.x + threadIdx.x) * 4;
  if (i >= n) return;
  float4 v = *(const float4*)(in + i);
  out[i + 0] = __float2bfloat16(v.x);
  out[i + 1] = __float2bfloat16(v.y);
  out[i + 2] = __float2bfloat16(v.z);
  out[i + 3] = __float2bfloat16(v.w);
}

// sent [Bh][L=256][E=512] f32 -> out [Bh][E][L] bf16
__global__ void transpose_cast(const float* __restrict__ in,
                               __hip_bfloat16* __restrict__ out) {
  __shared__ float tile[32][33];
  const int b = blockIdx.z;
  const int e0 = blockIdx.x * 32;
  const int l0 = blockIdx.y * 32;
  const float* ib = in + (long)b * 256 * 512;
  __hip_bfloat16* ob = out + (long)b * 256 * 512;
  const int tx = threadIdx.x, ty = threadIdx.y;
#pragma unroll
  for (int k = 0; k < 4; ++k)
    tile[ty + 8 * k][tx] = ib[(long)(l0 + ty + 8 * k) * 512 + e0 + tx];
  __syncthreads();
#pragma unroll
  for (int k = 0; k < 4; ++k)
    ob[(long)(e0 + ty + 8 * k) * 256 + l0 + tx] =
        __float2bfloat16(tile[tx][ty + 8 * k]);
}

// fill concat right half: out[row*1024 + 512 + c] = bf16(in[row*512+c])
__global__ void concat_fill(const float* __restrict__ in,
                            __hip_bfloat16* __restrict__ out) {
  const long i = (long)blockIdx.x * 256 + threadIdx.x;
  const long row = i >> 9;
  const int c = (int)(i & 511);
  out[row * 1024 + 512 + c] = __float2bfloat16(in[i]);
}

// row softmax over 256 cols: E fp32 [rows][256] -> W bf16 (coalesced)
__global__ void softmax_rows(const float* __restrict__ E,
                             __hip_bfloat16* __restrict__ W) {
  const long row = blockIdx.x;
  const int t = threadIdx.x;
  const float x = E[row * 256 + t];
  float m = x;
  for (int o = 32; o > 0; o >>= 1) m = fmaxf(m, __shfl_xor(m, o));
  __shared__ float red[4];
  if ((t & 63) == 0) red[t >> 6] = m;
  __syncthreads();
  m = fmaxf(fmaxf(red[0], red[1]), fmaxf(red[2], red[3]));
  const float pr = __expf(x - m);
  float s = pr;
  for (int o = 32; o > 0; o >>= 1) s += __shfl_xor(s, o);
  __shared__ float red2[4];
  if ((t & 63) == 0) red2[t >> 6] = s;
  __syncthreads();
  s = red2[0] + red2[1] + red2[2] + red2[3];
  W[row * 256 + t] = __float2bfloat16(pr / s);
}

// column softmax pass 1: per (b, j) max & inv-sum over i. grid (4, Bh).
__global__ __launch_bounds__(256) void col_stats(const float* __restrict__ E,
                                                 float* __restrict__ Mb,
                                                 float* __restrict__ Sb) {
  const int b = blockIdx.y;
  const int j0 = blockIdx.x * 64;
  const int jl = threadIdx.x & 63, s = threadIdx.x >> 6;
  const float* Eb = E + (long)b * 65536 + j0 + jl;
  float m = -3.4e38f;
  for (int r = 0; r < 64; ++r) m = fmaxf(m, Eb[(long)(s * 64 + r) * 256]);
  __shared__ float mr[4][64], sr[4][64];
  mr[s][jl] = m;
  __syncthreads();
  m = fmaxf(fmaxf(mr[0][jl], mr[1][jl]), fmaxf(mr[2][jl], mr[3][jl]));
  float sum = 0.f;
  for (int r = 0; r < 64; ++r) sum += __expf(Eb[(long)(s * 64 + r) * 256] - m);
  sr[s][jl] = sum;
  __syncthreads();
  if (s == 0) {
    sum = sr[0][jl] + sr[1][jl] + sr[2][jl] + sr[3][jl];
    Mb[b * 256 + j0 + jl] = m;
    Sb[b * 256 + j0 + jl] = 1.0f / sum;
  }
}

// column softmax pass 2: W[b][j][i] via 64x64 LDS transpose. grid (4,4,Bh).
__global__ __launch_bounds__(256) void softmax_cols_t(
    const float* __restrict__ E, const float* __restrict__ Mb,
    const float* __restrict__ Sb, __hip_bfloat16* __restrict__ W) {
  __shared__ float tile[64][65];
  const int b = blockIdx.z;
  const int i0 = blockIdx.x * 64;
  const int j0 = blockIdx.y * 64;
  const float* Eb = E + (long)b * 65536;
  const int tx = threadIdx.x & 63, ty = threadIdx.x >> 6;
#pragma unroll
  for (int k = 0; k < 16; ++k) {
    const int r = k * 4 + ty;
    tile[r][tx] = Eb[(long)(i0 + r) * 256 + j0 + tx];
  }
  __syncthreads();
#pragma unroll
  for (int k = 0; k < 16; ++k) {
    const int j = j0 + k * 4 + ty;
    const float mj = Mb[b * 256 + j];
    const float sj = Sb[b * 256 + j];
    const float v = __expf(tile[tx][k * 4 + ty] - mj) * sj;
    W[(long)b * 65536 + (long)j * 256 + i0 + tx] = __float2bfloat16(v);
  }
}

// out[b][o] = sum_h h2[b][h]*fin_w[o][h] + fin_b[o]
__global__ void final_lin(const __hip_bfloat16* __restrict__ h2,
                          const float* __restrict__ w,
                          const float* __restrict__ bs,
                          float* __restrict__ out) {
  const int b = blockIdx.x;
  const int t = threadIdx.x;
  float p0 = 0.f, p1 = 0.f, p2 = 0.f;
  for (int k = t; k < 1024; k += 256) {
    const float x = __bfloat162float(h2[(long)b * 1024 + k]);
    p0 += x * w[k];
    p1 += x * w[1024 + k];
    p2 += x * w[2048 + k];
  }
  for (int o = 32; o > 0; o >>= 1) {
    p0 += __shfl_xor(p0, o);
    p1 += __shfl_xor(p1, o);
    p2 += __shfl_xor(p2, o);
  }
  __shared__ float r[4][3];
  if ((t & 63) == 0) {
    r[t >> 6][0] = p0;
    r[t >> 6][1] = p1;
    r[t >> 6][2] = p2;
  }
  __syncthreads();
  if (t < 3)
    out[b * 3 + t] = r[0][t] + r[1][t] + r[2][t] + r[3][t] + bs[t];
}

extern "C" void kernel_launch(void* const* d_in, const int* in_sizes, int n_in,
                              void* d_out, int out_size, void* d_ws,
                              size_t ws_size, hipStream_t stream) {
  const float* sent1 = (const float*)d_in[0];
  const float* sent2 = (const float*)d_in[1];
  const float* f_w1 = (const float*)d_in[2];
  const float* f_b1 = (const float*)d_in[3];
  const float* f_w2 = (const float*)d_in[4];
  const float* f_b2 = (const float*)d_in[5];
  const float* g_w1 = (const float*)d_in[6];
  const float* g_b1 = (const float*)d_in[7];
  const float* g_w2 = (const float*)d_in[8];
  const float* g_b2 = (const float*)d_in[9];
  const float* h_w1 = (const float*)d_in[10];
  const float* h_b1 = (const float*)d_in[11];
  const float* h_w2 = (const float*)d_in[12];
  const float* h_b2 = (const float*)d_in[13];
  const float* fin_w = (const float*)d_in[14];
  const float* fin_b = (const float*)d_in[15];

  char* p = (char*)d_ws;
  auto take = [&](size_t n) {
    char* r = p;
    p += (n + 255) & ~(size_t)255;
    return r;
  };
  // Chunk size: Bh batches per side per chunk; merged-side GEMMs are M=2*R.
  const int Bh = (ws_size >= (size_t)220 * 1024 * 1024) ? 64 : 32;
  const int chunks = 128 / Bh;
  const long R = (long)Bh * 256;  // rows per side per chunk

  // weights (bf16)
  short* Wf1 = (short*)take(1024L * 512 * 2);
  short* Wf2 = (short*)take(1024L * 1024 * 2);
  short* Wg1 = (short*)take(1024L * 1024 * 2);
  short* Wg2 = (short*)take(1024L * 1024 * 2);
  short* Wh1 = (short*)take(1024L * 2048 * 2);
  short* Wh2 = (short*)take(1024L * 1024 * 2);
  float* SUMF = (float*)take(128L * 2048 * 4);
  short* scat = (short*)take(128L * 2048 * 2);
  short* hh = (short*)take(128L * 1024 * 2);
  short* hf = (short*)take(128L * 1024 * 2);
  float* Mb = (float*)take((long)Bh * 256 * 4);
  float* Sb = (float*)take((long)Bh * 256 * 4);
  // big aliased regions
  char* Areg = take(2 * R * 1024 * 2);  // FHID -> GHID   [2R,1024] bf16
  char* Breg = take(2 * R * 1024 * 2);  // F12  -> CC12   [2R,1024] bf16
  char* Creg = take(2 * R * 512 * 2);   // S12b -> E1|W1A|W2A
  char* Dreg = take(2 * R * 512 * 2);   // S12T
  (void)in_sizes; (void)n_in; (void)out_size;

  short* FHID = (short*)Areg;
  short* GHID = (short*)Areg;
  short* F12 = (short*)Breg;
  short* CC12 = (short*)Breg;
  short* S12b = (short*)Creg;
  float* E1 = (float*)Creg;
  short* W1A = (short*)(Creg + (long)Bh * 262144);
  short* W2A = W1A + (long)Bh * 65536;
  short* S1T = (short*)Dreg;
  short* S2T = S1T + R * 512;

  hipMemsetAsync(SUMF, 0, 128L * 2048 * 4, stream);

  // ---- weight casts (once) ----
  cast_bf16<<<512, 256, 0, stream>>>(f_w1, (__hip_bfloat16*)Wf1, 524288);
  cast_bf16<<<1024, 256, 0, stream>>>(f_w2, (__hip_bfloat16*)Wf2, 1048576);
  cast_bf16<<<1024, 256, 0, stream>>>(g_w1, (__hip_bfloat16*)Wg1, 1048576);
  cast_bf16<<<1024, 256, 0, stream>>>(g_w2, (__hip_bfloat16*)Wg2, 1048576);
  cast_bf16<<<2048, 256, 0, stream>>>(h_w1, (__hip_bfloat16*)Wh1, 2097152);
  cast_bf16<<<1024, 256, 0, stream>>>(h_w2, (__hip_bfloat16*)Wh2, 1048576);

  for (int c = 0; c < chunks; ++c) {
    const float* s1 = sent1 + (long)c * R * 512;
    const float* s2 = sent2 + (long)c * R * 512;
    float* SUMF_c = SUMF + (long)c * Bh * 2048;
    const int MT = (int)(2 * R / 128);  // merged M-tiles

    cast_bf16<<<R / 2, 256, 0, stream>>>(s1, (__hip_bfloat16*)S12b, R * 512);
    cast_bf16<<<R / 2, 256, 0, stream>>>(s2, (__hip_bfloat16*)(S12b + R * 512),
                                         R * 512);
    transpose_cast<<<dim3(16, 8, Bh), dim3(32, 8), 0, stream>>>(
        s1, (__hip_bfloat16*)S1T);
    transpose_cast<<<dim3(16, 8, Bh), dim3(32, 8), 0, stream>>>(
        s2, (__hip_bfloat16*)S2T);

    // ---- attend MLP f (merged sides, M = 2R) ----
    gemm_nt<true, true, true, false><<<dim3(8, MT, 1), 256, 0, stream>>>(
        S12b, Wf1, f_b1, FHID, 512, 512, 512, 1024, 0, 0, 0);
    gemm_nt<true, true, true, false><<<dim3(8, MT, 1), 256, 0, stream>>>(
        FHID, Wf2, f_b2, F12, 1024, 1024, 1024, 1024, 0, 0, 0);

    // ---- e1 = F1 F2^T (batched, fp32 out; overwrites S12b region) ----
    gemm_nt<false, false, false, false><<<dim3(2, 2, Bh), 256, 0, stream>>>(
        F12, F12 + R * 1024, nullptr, E1, 1024, 1024, 1024, 256, 256L * 1024,
        256L * 1024, 65536);

    // ---- softmaxes ----
    softmax_rows<<<Bh * 256, 256, 0, stream>>>(E1, (__hip_bfloat16*)W1A);
    col_stats<<<dim3(4, Bh), 256, 0, stream>>>(E1, Mb, Sb);
    softmax_cols_t<<<dim3(4, 4, Bh), 256, 0, stream>>>(E1, Mb, Sb,
                                                       (__hip_bfloat16*)W2A);

    // ---- att into concat buffers (CC12 overwrites F12) ----
    gemm_nt<false, true, false, false><<<dim3(4, 2, Bh), 256, 0, stream>>>(
        W1A, S2T, nullptr, CC12, 256, 256, 256, 1024, 65536, 131072, 262144);
    concat_fill<<<R * 2, 256, 0, stream>>>(s1, (__hip_bfloat16*)CC12);
    gemm_nt<false, true, false, false><<<dim3(4, 2, Bh), 256, 0, stream>>>(
        W2A, S1T, nullptr, CC12 + R * 1024, 256, 256, 256, 1024, 65536, 131072,
        262144);
    concat_fill<<<R * 2, 256, 0, stream>>>(
        s2, (__hip_bfloat16*)(CC12 + R * 1024));

    // ---- compare MLP g (merged); layer2 accumulates sum-over-L ----
    gemm_nt<true, true, true, false><<<dim3(8, MT, 1), 256, 0, stream>>>(
        CC12, Wg1, g_b1, GHID, 1024, 1024, 1024, 1024, 0, 0, 0);
    gemm_nt<true, false, true, true><<<dim3(8, MT, 1), 256, 0, stream>>>(
        GHID, Wg2, g_b2, SUMF_c, 1024, 1024, 1024, 2048, 0, 0, Bh);
  }

  // ---- aggregate MLP h + final linear ----
  cast_bf16<<<256, 256, 0, stream>>>(SUMF, (__hip_bfloat16*)scat, 262144);
  gemm_nt<true, true, true, false><<<dim3(8, 1, 1), 256, 0, stream>>>(
      scat, Wh1, h_b1, hh, 2048, 2048, 2048, 1024, 0, 0, 0);
  gemm_nt<true, true, true, false><<<dim3(8, 1, 1), 256, 0, stream>>>(
      hh, Wh2, h_b2, hf, 1024, 1024, 1024, 1024, 0, 0, 0);
  final_lin<<<128, 256, 0, stream>>>((__hip_bfloat16*)hf, fin_w, fin_b,
                                     (float*)d_out);
}

// Round 5
// 1122.452 us; speedup vs baseline: 1.3368x; 1.1025x over previous
//
#include <hip/hip_runtime.h>
#include <hip/hip_bf16.h>

// Decomposable attention, bf16-MFMA pipeline, chunked (Bh per side per chunk).
// R5: XOR-swizzled LDS layout in gemm_nt (kills 8-way bank conflicts on
// ds_read_b128); fused prep (cast+transpose, both sents, 1 launch); merged
// att GEMM (z=2*Bh); merged concat; fused column softmax; 1-launch wt casts.

using f32x4 = __attribute__((ext_vector_type(4))) float;
using s16x8 = __attribute__((ext_vector_type(8))) short;

__device__ __forceinline__ void gload_lds16(const short* g, short* l) {
  __builtin_amdgcn_global_load_lds(
      (const __attribute__((address_space(1))) unsigned int*)g,
      (__attribute__((address_space(3))) unsigned int*)l, 16, 0, 0);
}

// ---------------- GEMM: C[M,N] = A[M,K] * B[N,K]^T (+bias, relu) ----------------
// grid = (N/128, M/128, batch), block = 256.
// LDS layout: row r, 16B-chunk c stored at slot c ^ ((r>>1)&3)  (XOR swizzle,
// 2-way max bank aliasing on both staging stores and b128 fragment reads).
// SUML: accumulate sum over rows per 256-row batch into float Cv; sC = split.
template <bool RELU, bool OUT_BF16, bool HAS_BIAS, bool SUML>
__global__ __launch_bounds__(256) void gemm_nt(
    const short* __restrict__ A, const short* __restrict__ B,
    const float* __restrict__ bias, void* __restrict__ Cv, int K, int lda,
    int ldb, int ldc, long sA, long sB, long sC) {
  __shared__ __align__(16) short As[128 * 32];
  __shared__ __align__(16) short Bs[128 * 32];
  const int t = threadIdx.x;
  const int lane = t & 63;
  const int wave = t >> 6;

  // XCD-aware swizzle (flat%8 ~ XCD): contiguous tile range per XCD.
  unsigned flat = (blockIdx.z * gridDim.y + blockIdx.y) * gridDim.x + blockIdx.x;
  const unsigned total = gridDim.x * gridDim.y * gridDim.z;
  unsigned bx = blockIdx.x, by = blockIdx.y, bz = blockIdx.z;
  if ((total & 7u) == 0) {
    unsigned nf = (flat & 7u) * (total >> 3) + (flat >> 3);
    bx = nf % gridDim.x;
    unsigned rest = nf / gridDim.x;
    by = rest % gridDim.y;
    bz = rest / gridDim.y;
  }
  const int m0 = by * 128;
  const int n0 = bx * 128;
  const long zb = bz;
  const short* Ab = A + zb * sA;
  const short* Bb = B + zb * sB;

  // staging: thread t fills LDS slot t (16B). row = t>>2, slot = t&3.
  // Fetch global chunk (t&3) ^ ((row>>1)&3) = (t&3) ^ ((t>>3)&3).
  const int swz = ((t & 3) ^ ((t >> 3) & 3)) * 8;
  const short* Ag = Ab + (long)(m0 + (t >> 2)) * lda + swz;
  const short* Bg = Bb + (long)(n0 + (t >> 2)) * ldb + swz;
  short* AsW = As + wave * 512;
  short* BsW = Bs + wave * 512;

  const int fr = lane & 15;
  const int kq = lane >> 4;  // 16B chunk index within BK=32 row
  int aoff[4], boff[4];
#pragma unroll
  for (int i = 0; i < 4; ++i) {
    const int ra = (wave >> 1) * 64 + i * 16 + fr;
    const int rb = (wave & 1) * 64 + i * 16 + fr;
    aoff[i] = ra * 32 + (kq ^ ((ra >> 1) & 3)) * 8;
    boff[i] = rb * 32 + (kq ^ ((rb >> 1) & 3)) * 8;
  }

  f32x4 acc[4][4] = {};

  for (int k0 = 0; k0 < K; k0 += 32) {
    gload_lds16(Ag + k0, AsW);
    gload_lds16(Ag + (long)64 * lda + k0, AsW + 2048);
    gload_lds16(Bg + k0, BsW);
    gload_lds16(Bg + (long)64 * ldb + k0, BsW + 2048);
    __syncthreads();
    s16x8 af[4], bfv[4];
#pragma unroll
    for (int i = 0; i < 4; ++i) af[i] = *(const s16x8*)(As + aoff[i]);
#pragma unroll
    for (int j = 0; j < 4; ++j) bfv[j] = *(const s16x8*)(Bs + boff[j]);
#pragma unroll
    for (int i = 0; i < 4; ++i)
#pragma unroll
      for (int j = 0; j < 4; ++j)
        acc[i][j] = __builtin_amdgcn_mfma_f32_16x16x32_bf16(af[i], bfv[j],
                                                            acc[i][j], 0, 0, 0);
    __syncthreads();
  }

  // C/D layout: col = lane&15, row = (lane>>4)*4 + reg  [m89/m91-verified]
  const int ccol = lane & 15;
  const int crow = (lane >> 4) * 4;

  if constexpr (SUML) {
    __shared__ float ssum[128];
    if (t < 128) ssum[t] = 0.f;
    __syncthreads();
#pragma unroll
    for (int j = 0; j < 4; ++j) {
      const int lcol = (wave & 1) * 64 + j * 16 + ccol;
      float bj = HAS_BIAS ? bias[n0 + lcol] : 0.f;
      float part = 0.f;
#pragma unroll
      for (int i = 0; i < 4; ++i)
#pragma unroll
        for (int r = 0; r < 4; ++r) {
          float x = acc[i][j][r] + bj;
          if (RELU) x = fmaxf(x, 0.f);
          part += x;
        }
      atomicAdd(&ssum[lcol], part);
    }
    __syncthreads();
    if (t < 128) {
      const int split = (int)sC;
      int rb2 = m0 >> 8;
      const int side = rb2 >= split;
      rb2 -= side * split;
      atomicAdd((float*)Cv + (long)rb2 * ldc + side * (ldc >> 1) + n0 + t,
                ssum[t]);
    }
  } else {
#pragma unroll
    for (int j = 0; j < 4; ++j) {
      const int col = n0 + (wave & 1) * 64 + j * 16 + ccol;
      float bj = 0.f;
      if (HAS_BIAS) bj = bias[col];
#pragma unroll
      for (int i = 0; i < 4; ++i) {
        const int row0 = m0 + (wave >> 1) * 64 + i * 16 + crow;
#pragma unroll
        for (int r = 0; r < 4; ++r) {
          float x = acc[i][j][r] + bj;
          if (RELU) x = fmaxf(x, 0.f);
          const long idx = (long)(row0 + r) * ldc + col + zb * sC;
          if (OUT_BF16)
            ((__hip_bfloat16*)Cv)[idx] = __float2bfloat16(x);
          else
            ((float*)Cv)[idx] = x;
        }
      }
    }
  }
}

// ---------------- helpers ----------------
struct CastArgs {
  const float* src[6];
  __hip_bfloat16* dst[6];
  long n[6];
};
__global__ void cast_many(CastArgs a) {
  const int w = blockIdx.y;
  long i = ((long)blockIdx.x * blockDim.x + threadIdx.x) * 4;
  if (i >= a.n[w]) return;
  float4 v = *(const float4*)(a.src[w] + i);
  __hip_bfloat16* o = a.dst[w] + i;
  o[0] = __float2bfloat16(v.x);
  o[1] = __float2bfloat16(v.y);
  o[2] = __float2bfloat16(v.z);
  o[3] = __float2bfloat16(v.w);
}

__global__ void cast_bf16(const float* __restrict__ in,
                          __hip_bfloat16* __restrict__ out, long n) {
  long i = ((long)blockIdx.x * blockDim.x + threadIdx.x) * 4;
  if (i >= n) return;
  float4 v = *(const float4*)(in + i);
  out[i + 0] = __float2bfloat16(v.x);
  out[i + 1] = __float2bfloat16(v.y);
  out[i + 2] = __float2bfloat16(v.z);
  out[i + 3] = __float2bfloat16(v.w);
}

// Fused sent prep: reads fp32 sent, writes row-major bf16 (S12b) AND
// transposed bf16 (ST). z < Bh -> sent1, else sent2. ST layout [S2T|S1T].
__global__ void prep_sent(const float* __restrict__ s1,
                          const float* __restrict__ s2,
                          __hip_bfloat16* __restrict__ S12b,
                          __hip_bfloat16* __restrict__ STbase, int Bh) {
  __shared__ float tile[32][33];
  const int z = blockIdx.z;
  const int e0 = blockIdx.x * 32;
  const int l0 = blockIdx.y * 32;
  const int side = z >= Bh;
  const int b = z - side * Bh;
  const float* ib = (side ? s2 : s1) + (long)b * 131072;
  __hip_bfloat16* on = S12b + (long)z * 131072;
  // [S2T | S1T] : side2 at offset 0, side1 after Bh batches
  __hip_bfloat16* ot =
      STbase + (long)(side ? b : (Bh + b)) * 131072;
  const int tx = threadIdx.x, ty = threadIdx.y;
#pragma unroll
  for (int k = 0; k < 4; ++k) {
    const int l = l0 + ty + 8 * k;
    const float v = ib[(long)l * 512 + e0 + tx];
    on[(long)l * 512 + e0 + tx] = __float2bfloat16(v);
    tile[ty + 8 * k][tx] = v;
  }
  __syncthreads();
#pragma unroll
  for (int k = 0; k < 4; ++k)
    ot[(long)(e0 + ty + 8 * k) * 256 + l0 + tx] =
        __float2bfloat16(tile[tx][ty + 8 * k]);
}

// merged concat right-half fill for both sides: CC12[row][512+c] = bf16(sent)
__global__ void concat_fill2(const float* __restrict__ s1,
                             const float* __restrict__ s2, long half_elems,
                             __hip_bfloat16* __restrict__ out) {
  const long i = ((long)blockIdx.x * 256 + threadIdx.x) * 4;
  const int side = i >= half_elems;
  const float* src = side ? s2 : s1;
  const long loc = i - (side ? half_elems : 0);
  float4 v = *(const float4*)(src + loc);
  const long row = i >> 9;
  const int c = (int)(i & 511);
  __hip_bfloat16* o = out + row * 1024 + 512 + c;
  o[0] = __float2bfloat16(v.x);
  o[1] = __float2bfloat16(v.y);
  o[2] = __float2bfloat16(v.z);
  o[3] = __float2bfloat16(v.w);
}

// row softmax over 256 cols: E fp32 [rows][256] -> W bf16 (coalesced)
__global__ void softmax_rows(const float* __restrict__ E,
                             __hip_bfloat16* __restrict__ W) {
  const long row = blockIdx.x;
  const int t = threadIdx.x;
  const float x = E[row * 256 + t];
  float m = x;
  for (int o = 32; o > 0; o >>= 1) m = fmaxf(m, __shfl_xor(m, o));
  __shared__ float red[4];
  if ((t & 63) == 0) red[t >> 6] = m;
  __syncthreads();
  m = fmaxf(fmaxf(red[0], red[1]), fmaxf(red[2], red[3]));
  const float pr = __expf(x - m);
  float s = pr;
  for (int o = 32; o > 0; o >>= 1) s += __shfl_xor(s, o);
  __shared__ float red2[4];
  if ((t & 63) == 0) red2[t >> 6] = s;
  __syncthreads();
  s = red2[0] + red2[1] + red2[2] + red2[3];
  W[row * 256 + t] = __float2bfloat16(pr / s);
}

// Fused column softmax: one pass. Block handles 64 columns (j) over all 256 i.
// Strip in LDS, stats, write W2A[b][j][i] transposed+coalesced. grid (4, Bh).
__global__ __launch_bounds__(256) void softmax_cols_f(
    const float* __restrict__ E, __hip_bfloat16* __restrict__ W) {
  __shared__ float tile[256][65];
  __shared__ float mred[4][64], sred[4][64];
  const int b = blockIdx.y;
  const int j0 = blockIdx.x * 64;
  const int t = threadIdx.x;
  const int jl = t & 63, s = t >> 6;
  const float* Eb = E + (long)b * 65536 + j0;
#pragma unroll
  for (int k = 0; k < 64; ++k) {
    const int i = k * 4 + s;
    tile[i][jl] = Eb[(long)i * 256 + jl];
  }
  __syncthreads();
  float m = -3.4e38f;
#pragma unroll 8
  for (int r = 0; r < 64; ++r) m = fmaxf(m, tile[s * 64 + r][jl]);
  mred[s][jl] = m;
  __syncthreads();
  m = fmaxf(fmaxf(mred[0][jl], mred[1][jl]), fmaxf(mred[2][jl], mred[3][jl]));
  float sum = 0.f;
#pragma unroll 8
  for (int r = 0; r < 64; ++r) sum += __expf(tile[s * 64 + r][jl] - m);
  sred[s][jl] = sum;
  __syncthreads();
  // stats for column jl finalized by all; each thread re-reads what it needs
  const int jw = t >> 2;           // j index this thread writes
  const int ib = t & 3;            // i block
  const float mj = fmaxf(fmaxf(mred[0][jw], mred[1][jw]),
                         fmaxf(mred[2][jw], mred[3][jw]));
  const float isj =
      1.0f / (sred[0][jw] + sred[1][jw] + sred[2][jw] + sred[3][jw]);
  __hip_bfloat16* Wb = W + (long)b * 65536 + (long)(j0 + jw) * 256 + ib * 64;
#pragma unroll 8
  for (int r = 0; r < 64; ++r)
    Wb[r] = __float2bfloat16(__expf(tile[ib * 64 + r][jw] - mj) * isj);
}

// out[b][o] = sum_h h2[b][h]*fin_w[o][h] + fin_b[o]
__global__ void final_lin(const __hip_bfloat16* __restrict__ h2,
                          const float* __restrict__ w,
                          const float* __restrict__ bs,
                          float* __restrict__ out) {
  const int b = blockIdx.x;
  const int t = threadIdx.x;
  float p0 = 0.f, p1 = 0.f, p2 = 0.f;
  for (int k = t; k < 1024; k += 256) {
    const float x = __bfloat162float(h2[(long)b * 1024 + k]);
    p0 += x * w[k];
    p1 += x * w[1024 + k];
    p2 += x * w[2048 + k];
  }
  for (int o = 32; o > 0; o >>= 1) {
    p0 += __shfl_xor(p0, o);
    p1 += __shfl_xor(p1, o);
    p2 += __shfl_xor(p2, o);
  }
  __shared__ float r[4][3];
  if ((t & 63) == 0) {
    r[t >> 6][0] = p0;
    r[t >> 6][1] = p1;
    r[t >> 6][2] = p2;
  }
  __syncthreads();
  if (t < 3)
    out[b * 3 + t] = r[0][t] + r[1][t] + r[2][t] + r[3][t] + bs[t];
}

extern "C" void kernel_launch(void* const* d_in, const int* in_sizes, int n_in,
                              void* d_out, int out_size, void* d_ws,
                              size_t ws_size, hipStream_t stream) {
  const float* sent1 = (const float*)d_in[0];
  const float* sent2 = (const float*)d_in[1];
  const float* f_w1 = (const float*)d_in[2];
  const float* f_b1 = (const float*)d_in[3];
  const float* f_w2 = (const float*)d_in[4];
  const float* f_b2 = (const float*)d_in[5];
  const float* g_w1 = (const float*)d_in[6];
  const float* g_b1 = (const float*)d_in[7];
  const float* g_w2 = (const float*)d_in[8];
  const float* g_b2 = (const float*)d_in[9];
  const float* h_w1 = (const float*)d_in[10];
  const float* h_b1 = (const float*)d_in[11];
  const float* h_w2 = (const float*)d_in[12];
  const float* h_b2 = (const float*)d_in[13];
  const float* fin_w = (const float*)d_in[14];
  const float* fin_b = (const float*)d_in[15];

  char* p = (char*)d_ws;
  auto take = [&](size_t n) {
    char* r = p;
    p += (n + 255) & ~(size_t)255;
    return r;
  };
  const int Bh = (ws_size >= (size_t)220 * 1024 * 1024) ? 64 : 32;
  const int chunks = 128 / Bh;
  const long R = (long)Bh * 256;  // rows per side per chunk

  short* Wf1 = (short*)take(1024L * 512 * 2);
  short* Wf2 = (short*)take(1024L * 1024 * 2);
  short* Wg1 = (short*)take(1024L * 1024 * 2);
  short* Wg2 = (short*)take(1024L * 1024 * 2);
  short* Wh1 = (short*)take(1024L * 2048 * 2);
  short* Wh2 = (short*)take(1024L * 1024 * 2);
  float* SUMF = (float*)take(128L * 2048 * 4);
  short* scat = (short*)take(128L * 2048 * 2);
  short* hh = (short*)take(128L * 1024 * 2);
  short* hf = (short*)take(128L * 1024 * 2);
  char* Areg = take(2 * R * 1024 * 2);  // FHID -> GHID
  char* Breg = take(2 * R * 1024 * 2);  // F12 -> CC12
  char* Creg = take(2 * R * 512 * 2);   // S12b -> E1|W1A|W2A
  char* Dreg = take(2 * R * 512 * 2);   // [S2T | S1T]
  (void)in_sizes; (void)n_in; (void)out_size;

  short* FHID = (short*)Areg;
  short* GHID = (short*)Areg;
  short* F12 = (short*)Breg;
  short* CC12 = (short*)Breg;
  short* S12b = (short*)Creg;
  float* E1 = (float*)Creg;
  short* W1A = (short*)(Creg + (long)Bh * 262144);
  short* W2A = W1A + (long)Bh * 65536;
  short* ST = (short*)Dreg;  // [S2T | S1T], batch stride 131072 elems

  hipMemsetAsync(SUMF, 0, 128L * 2048 * 4, stream);

  // ---- weight casts (one launch) ----
  CastArgs ca;
  ca.src[0] = f_w1; ca.dst[0] = (__hip_bfloat16*)Wf1; ca.n[0] = 524288;
  ca.src[1] = f_w2; ca.dst[1] = (__hip_bfloat16*)Wf2; ca.n[1] = 1048576;
  ca.src[2] = g_w1; ca.dst[2] = (__hip_bfloat16*)Wg1; ca.n[2] = 1048576;
  ca.src[3] = g_w2; ca.dst[3] = (__hip_bfloat16*)Wg2; ca.n[3] = 1048576;
  ca.src[4] = h_w1; ca.dst[4] = (__hip_bfloat16*)Wh1; ca.n[4] = 2097152;
  ca.src[5] = h_w2; ca.dst[5] = (__hip_bfloat16*)Wh2; ca.n[5] = 1048576;
  cast_many<<<dim3(2048, 6), 256, 0, stream>>>(ca);

  for (int c = 0; c < chunks; ++c) {
    const float* s1 = sent1 + (long)c * R * 512;
    const float* s2 = sent2 + (long)c * R * 512;
    float* SUMF_c = SUMF + (long)c * Bh * 2048;
    const int MT = (int)(2 * R / 128);

    prep_sent<<<dim3(16, 8, 2 * Bh), dim3(32, 8), 0, stream>>>(
        s1, s2, (__hip_bfloat16*)S12b, (__hip_bfloat16*)ST, Bh);

    // ---- attend MLP f (merged sides, M = 2R) ----
    gemm_nt<true, true, true, false><<<dim3(8, MT, 1), 256, 0, stream>>>(
        S12b, Wf1, f_b1, FHID, 512, 512, 512, 1024, 0, 0, 0);
    gemm_nt<true, true, true, false><<<dim3(8, MT, 1), 256, 0, stream>>>(
        FHID, Wf2, f_b2, F12, 1024, 1024, 1024, 1024, 0, 0, 0);

    // ---- e1 = F1 F2^T (batched fp32; overwrites S12b region) ----
    gemm_nt<false, false, false, false><<<dim3(2, 2, Bh), 256, 0, stream>>>(
        F12, F12 + R * 1024, nullptr, E1, 1024, 1024, 1024, 256, 256L * 1024,
        256L * 1024, 65536);

    // ---- softmaxes ----
    softmax_rows<<<Bh * 256, 256, 0, stream>>>(E1, (__hip_bfloat16*)W1A);
    softmax_cols_f<<<dim3(4, Bh), 256, 0, stream>>>(E1, (__hip_bfloat16*)W2A);

    // ---- att (merged: z<Bh -> att1 from (W1A,S2T); z>=Bh -> att2 (W2A,S1T))
    // W1A/W2A contiguous; ST = [S2T|S1T]; C halves contiguous in CC12.
    gemm_nt<false, true, false, false><<<dim3(4, 2, 2 * Bh), 256, 0, stream>>>(
        W1A, ST, nullptr, CC12, 256, 256, 256, 1024, 65536, 131072, 262144);
    concat_fill2<<<(unsigned)(2 * R * 512 / 1024), 256, 0, stream>>>(
        s1, s2, R * 512, (__hip_bfloat16*)CC12);

    // ---- compare MLP g (merged); layer2 accumulates sum-over-L ----
    gemm_nt<true, true, true, false><<<dim3(8, MT, 1), 256, 0, stream>>>(
        CC12, Wg1, g_b1, GHID, 1024, 1024, 1024, 1024, 0, 0, 0);
    gemm_nt<true, false, true, true><<<dim3(8, MT, 1), 256, 0, stream>>>(
        GHID, Wg2, g_b2, SUMF_c, 1024, 1024, 1024, 2048, 0, 0, Bh);
  }

  // ---- aggregate MLP h + final linear ----
  cast_bf16<<<256, 256, 0, stream>>>(SUMF, (__hip_bfloat16*)scat, 262144);
  gemm_nt<true, true, true, false><<<dim3(8, 1, 1), 256, 0, stream>>>(
      scat, Wh1, h_b1, hh, 2048, 2048, 2048, 1024, 0, 0, 0);
  gemm_nt<true, true, true, false><<<dim3(8, 1, 1), 256, 0, stream>>>(
      hh, Wh2, h_b2, hf, 1024, 1024, 1024, 1024, 0, 0, 0);
  final_lin<<<128, 256, 0, stream>>>((__hip_bfloat16*)hf, fin_w, fin_b,
                                     (float*)d_out);
}

// Round 6
// 1109.859 us; speedup vs baseline: 1.3520x; 1.0113x over previous
//
#include <hip/hip_runtime.h>
#include <hip/hip_bf16.h>

// Decomposable attention, bf16-MFMA pipeline, chunked (Bh per side per chunk).
// R6: __launch_bounds__(256,4) to push gemm_nt to 4 waves/SIMD (reg cap 128);
// pointer-bump staging addresses; concat fused into att-GEMM epilogue.

using f32x4 = __attribute__((ext_vector_type(4))) float;
using s16x8 = __attribute__((ext_vector_type(8))) short;

__device__ __forceinline__ void gload_lds16(const short* g, short* l) {
  __builtin_amdgcn_global_load_lds(
      (const __attribute__((address_space(1))) unsigned int*)g,
      (__attribute__((address_space(3))) unsigned int*)l, 16, 0, 0);
}

// ---------------- GEMM: C[M,N] = A[M,K] * B[N,K]^T (+bias, relu) ----------------
// grid = (N/128, M/128, batch), block = 256.
// LDS XOR swizzle: row r chunk c at slot c ^ ((r>>1)&3) — 0 bank conflicts (R5).
// SUML: row-sum per 256-row batch into float Cv; sC = split.
// CONCAT: att epilogue also fills right concat half from fp32 sent (cs1/cs2).
template <bool RELU, bool OUT_BF16, bool HAS_BIAS, bool SUML, bool CONCAT>
__global__ __launch_bounds__(256, 4) void gemm_nt(
    const short* __restrict__ A, const short* __restrict__ B,
    const float* __restrict__ bias, void* __restrict__ Cv, int K, int lda,
    int ldb, int ldc, long sA, long sB, long sC, const float* __restrict__ cs1,
    const float* __restrict__ cs2, int cBh) {
  __shared__ __align__(16) short As[128 * 32];
  __shared__ __align__(16) short Bs[128 * 32];
  const int t = threadIdx.x;
  const int lane = t & 63;
  const int wave = t >> 6;

  // XCD-aware swizzle (flat%8 ~ XCD): contiguous tile range per XCD.
  unsigned flat = (blockIdx.z * gridDim.y + blockIdx.y) * gridDim.x + blockIdx.x;
  const unsigned total = gridDim.x * gridDim.y * gridDim.z;
  unsigned bx = blockIdx.x, by = blockIdx.y, bz = blockIdx.z;
  if ((total & 7u) == 0) {
    unsigned nf = (flat & 7u) * (total >> 3) + (flat >> 3);
    bx = nf % gridDim.x;
    unsigned rest = nf / gridDim.x;
    by = rest % gridDim.y;
    bz = rest / gridDim.y;
  }
  const int m0 = by * 128;
  const int n0 = bx * 128;
  const long zb = bz;

  // staging: thread t fills LDS slot t (16B); fetches swizzled global chunk.
  const int swz = ((t & 3) ^ ((t >> 3) & 3)) * 8;
  const short* ag0 = A + zb * sA + (long)(m0 + (t >> 2)) * lda + swz;
  const short* ag1 = ag0 + (long)64 * lda;
  const short* bg0 = B + zb * sB + (long)(n0 + (t >> 2)) * ldb + swz;
  const short* bg1 = bg0 + (long)64 * ldb;
  short* AsW = As + wave * 512;
  short* BsW = Bs + wave * 512;

  const int fr = lane & 15;
  const int kq = lane >> 4;
  int aoff[4], boff[4];
#pragma unroll
  for (int i = 0; i < 4; ++i) {
    const int ra = (wave >> 1) * 64 + i * 16 + fr;
    const int rb = (wave & 1) * 64 + i * 16 + fr;
    aoff[i] = ra * 32 + (kq ^ ((ra >> 1) & 3)) * 8;
    boff[i] = rb * 32 + (kq ^ ((rb >> 1) & 3)) * 8;
  }

  f32x4 acc[4][4] = {};

  for (int it = K >> 5; it > 0; --it) {
    gload_lds16(ag0, AsW);
    gload_lds16(ag1, AsW + 2048);
    gload_lds16(bg0, BsW);
    gload_lds16(bg1, BsW + 2048);
    ag0 += 32; ag1 += 32; bg0 += 32; bg1 += 32;
    __syncthreads();
    s16x8 af[4], bfv[4];
#pragma unroll
    for (int i = 0; i < 4; ++i) af[i] = *(const s16x8*)(As + aoff[i]);
#pragma unroll
    for (int j = 0; j < 4; ++j) bfv[j] = *(const s16x8*)(Bs + boff[j]);
#pragma unroll
    for (int i = 0; i < 4; ++i)
#pragma unroll
      for (int j = 0; j < 4; ++j)
        acc[i][j] = __builtin_amdgcn_mfma_f32_16x16x32_bf16(af[i], bfv[j],
                                                            acc[i][j], 0, 0, 0);
    __syncthreads();
  }

  // C/D layout: col = lane&15, row = (lane>>4)*4 + reg  [m89/m91-verified]
  const int ccol = lane & 15;
  const int crow = (lane >> 4) * 4;

  if constexpr (SUML) {
    __shared__ float ssum[128];
    if (t < 128) ssum[t] = 0.f;
    __syncthreads();
#pragma unroll
    for (int j = 0; j < 4; ++j) {
      const int lcol = (wave & 1) * 64 + j * 16 + ccol;
      float bj = HAS_BIAS ? bias[n0 + lcol] : 0.f;
      float part = 0.f;
#pragma unroll
      for (int i = 0; i < 4; ++i)
#pragma unroll
        for (int r = 0; r < 4; ++r) {
          float x = acc[i][j][r] + bj;
          if (RELU) x = fmaxf(x, 0.f);
          part += x;
        }
      atomicAdd(&ssum[lcol], part);
    }
    __syncthreads();
    if (t < 128) {
      const int split = (int)sC;
      int rb2 = m0 >> 8;
      const int side = rb2 >= split;
      rb2 -= side * split;
      atomicAdd((float*)Cv + (long)rb2 * ldc + side * (ldc >> 1) + n0 + t,
                ssum[t]);
    }
  } else {
    const float* csrc = nullptr;
    long crowbase = 0;
    if constexpr (CONCAT) {
      const int side = (int)(zb >= (long)cBh);
      const int bb = (int)zb - side * cBh;
      csrc = side ? cs2 : cs1;
      crowbase = (long)bb * 256;
    }
#pragma unroll
    for (int j = 0; j < 4; ++j) {
      const int col = n0 + (wave & 1) * 64 + j * 16 + ccol;
      float bj = 0.f;
      if (HAS_BIAS) bj = bias[col];
#pragma unroll
      for (int i = 0; i < 4; ++i) {
        const int row0 = m0 + (wave >> 1) * 64 + i * 16 + crow;
#pragma unroll
        for (int r = 0; r < 4; ++r) {
          float x = acc[i][j][r] + bj;
          if (RELU) x = fmaxf(x, 0.f);
          const long idx = (long)(row0 + r) * ldc + col + zb * sC;
          if (OUT_BF16)
            ((__hip_bfloat16*)Cv)[idx] = __float2bfloat16(x);
          else
            ((float*)Cv)[idx] = x;
          if constexpr (CONCAT) {
            const float v = csrc[(crowbase + row0 + r) * 512 + col];
            ((__hip_bfloat16*)Cv)[idx + 512] = __float2bfloat16(v);
          }
        }
      }
    }
  }
}

// ---------------- helpers ----------------
struct CastArgs {
  const float* src[6];
  __hip_bfloat16* dst[6];
  long n[6];
};
__global__ void cast_many(CastArgs a) {
  const int w = blockIdx.y;
  long i = ((long)blockIdx.x * blockDim.x + threadIdx.x) * 4;
  if (i >= a.n[w]) return;
  float4 v = *(const float4*)(a.src[w] + i);
  __hip_bfloat16* o = a.dst[w] + i;
  o[0] = __float2bfloat16(v.x);
  o[1] = __float2bfloat16(v.y);
  o[2] = __float2bfloat16(v.z);
  o[3] = __float2bfloat16(v.w);
}

__global__ void cast_bf16(const float* __restrict__ in,
                          __hip_bfloat16* __restrict__ out, long n) {
  long i = ((long)blockIdx.x * blockDim.x + threadIdx.x) * 4;
  if (i >= n) return;
  float4 v = *(const float4*)(in + i);
  out[i + 0] = __float2bfloat16(v.x);
  out[i + 1] = __float2bfloat16(v.y);
  out[i + 2] = __float2bfloat16(v.z);
  out[i + 3] = __float2bfloat16(v.w);
}

// Fused sent prep: fp32 sent -> row-major bf16 (S12b) AND transposed bf16
// (ST = [S2T|S1T]). z < Bh -> sent1, else sent2.
__global__ void prep_sent(const float* __restrict__ s1,
                          const float* __restrict__ s2,
                          __hip_bfloat16* __restrict__ S12b,
                          __hip_bfloat16* __restrict__ STbase, int Bh) {
  __shared__ float tile[32][33];
  const int z = blockIdx.z;
  const int e0 = blockIdx.x * 32;
  const int l0 = blockIdx.y * 32;
  const int side = z >= Bh;
  const int b = z - side * Bh;
  const float* ib = (side ? s2 : s1) + (long)b * 131072;
  __hip_bfloat16* on = S12b + (long)z * 131072;
  __hip_bfloat16* ot = STbase + (long)(side ? b : (Bh + b)) * 131072;
  const int tx = threadIdx.x, ty = threadIdx.y;
#pragma unroll
  for (int k = 0; k < 4; ++k) {
    const int l = l0 + ty + 8 * k;
    const float v = ib[(long)l * 512 + e0 + tx];
    on[(long)l * 512 + e0 + tx] = __float2bfloat16(v);
    tile[ty + 8 * k][tx] = v;
  }
  __syncthreads();
#pragma unroll
  for (int k = 0; k < 4; ++k)
    ot[(long)(e0 + ty + 8 * k) * 256 + l0 + tx] =
        __float2bfloat16(tile[tx][ty + 8 * k]);
}

// row softmax over 256 cols: E fp32 [rows][256] -> W bf16 (coalesced)
__global__ void softmax_rows(const float* __restrict__ E,
                             __hip_bfloat16* __restrict__ W) {
  const long row = blockIdx.x;
  const int t = threadIdx.x;
  const float x = E[row * 256 + t];
  float m = x;
  for (int o = 32; o > 0; o >>= 1) m = fmaxf(m, __shfl_xor(m, o));
  __shared__ float red[4];
  if ((t & 63) == 0) red[t >> 6] = m;
  __syncthreads();
  m = fmaxf(fmaxf(red[0], red[1]), fmaxf(red[2], red[3]));
  const float pr = __expf(x - m);
  float s = pr;
  for (int o = 32; o > 0; o >>= 1) s += __shfl_xor(s, o);
  __shared__ float red2[4];
  if ((t & 63) == 0) red2[t >> 6] = s;
  __syncthreads();
  s = red2[0] + red2[1] + red2[2] + red2[3];
  W[row * 256 + t] = __float2bfloat16(pr / s);
}

// Fused column softmax: strip in LDS, stats, transposed coalesced write.
__global__ __launch_bounds__(256) void softmax_cols_f(
    const float* __restrict__ E, __hip_bfloat16* __restrict__ W) {
  __shared__ float tile[256][65];
  __shared__ float mred[4][64], sred[4][64];
  const int b = blockIdx.y;
  const int j0 = blockIdx.x * 64;
  const int t = threadIdx.x;
  const int jl = t & 63, s = t >> 6;
  const float* Eb = E + (long)b * 65536 + j0;
#pragma unroll
  for (int k = 0; k < 64; ++k) {
    const int i = k * 4 + s;
    tile[i][jl] = Eb[(long)i * 256 + jl];
  }
  __syncthreads();
  float m = -3.4e38f;
#pragma unroll 8
  for (int r = 0; r < 64; ++r) m = fmaxf(m, tile[s * 64 + r][jl]);
  mred[s][jl] = m;
  __syncthreads();
  m = fmaxf(fmaxf(mred[0][jl], mred[1][jl]), fmaxf(mred[2][jl], mred[3][jl]));
  float sum = 0.f;
#pragma unroll 8
  for (int r = 0; r < 64; ++r) sum += __expf(tile[s * 64 + r][jl] - m);
  sred[s][jl] = sum;
  __syncthreads();
  const int jw = t >> 2;
  const int ib = t & 3;
  const float mj = fmaxf(fmaxf(mred[0][jw], mred[1][jw]),
                         fmaxf(mred[2][jw], mred[3][jw]));
  const float isj =
      1.0f / (sred[0][jw] + sred[1][jw] + sred[2][jw] + sred[3][jw]);
  __hip_bfloat16* Wb = W + (long)b * 65536 + (long)(j0 + jw) * 256 + ib * 64;
#pragma unroll 8
  for (int r = 0; r < 64; ++r)
    Wb[r] = __float2bfloat16(__expf(tile[ib * 64 + r][jw] - mj) * isj);
}

// out[b][o] = sum_h h2[b][h]*fin_w[o][h] + fin_b[o]
__global__ void final_lin(const __hip_bfloat16* __restrict__ h2,
                          const float* __restrict__ w,
                          const float* __restrict__ bs,
                          float* __restrict__ out) {
  const int b = blockIdx.x;
  const int t = threadIdx.x;
  float p0 = 0.f, p1 = 0.f, p2 = 0.f;
  for (int k = t; k < 1024; k += 256) {
    const float x = __bfloat162float(h2[(long)b * 1024 + k]);
    p0 += x * w[k];
    p1 += x * w[1024 + k];
    p2 += x * w[2048 + k];
  }
  for (int o = 32; o > 0; o >>= 1) {
    p0 += __shfl_xor(p0, o);
    p1 += __shfl_xor(p1, o);
    p2 += __shfl_xor(p2, o);
  }
  __shared__ float r[4][3];
  if ((t & 63) == 0) {
    r[t >> 6][0] = p0;
    r[t >> 6][1] = p1;
    r[t >> 6][2] = p2;
  }
  __syncthreads();
  if (t < 3)
    out[b * 3 + t] = r[0][t] + r[1][t] + r[2][t] + r[3][t] + bs[t];
}

extern "C" void kernel_launch(void* const* d_in, const int* in_sizes, int n_in,
                              void* d_out, int out_size, void* d_ws,
                              size_t ws_size, hipStream_t stream) {
  const float* sent1 = (const float*)d_in[0];
  const float* sent2 = (const float*)d_in[1];
  const float* f_w1 = (const float*)d_in[2];
  const float* f_b1 = (const float*)d_in[3];
  const float* f_w2 = (const float*)d_in[4];
  const float* f_b2 = (const float*)d_in[5];
  const float* g_w1 = (const float*)d_in[6];
  const float* g_b1 = (const float*)d_in[7];
  const float* g_w2 = (const float*)d_in[8];
  const float* g_b2 = (const float*)d_in[9];
  const float* h_w1 = (const float*)d_in[10];
  const float* h_b1 = (const float*)d_in[11];
  const float* h_w2 = (const float*)d_in[12];
  const float* h_b2 = (const float*)d_in[13];
  const float* fin_w = (const float*)d_in[14];
  const float* fin_b = (const float*)d_in[15];

  char* p = (char*)d_ws;
  auto take = [&](size_t n) {
    char* r = p;
    p += (n + 255) & ~(size_t)255;
    return r;
  };
  const int Bh = (ws_size >= (size_t)220 * 1024 * 1024) ? 64 : 32;
  const int chunks = 128 / Bh;
  const long R = (long)Bh * 256;

  short* Wf1 = (short*)take(1024L * 512 * 2);
  short* Wf2 = (short*)take(1024L * 1024 * 2);
  short* Wg1 = (short*)take(1024L * 1024 * 2);
  short* Wg2 = (short*)take(1024L * 1024 * 2);
  short* Wh1 = (short*)take(1024L * 2048 * 2);
  short* Wh2 = (short*)take(1024L * 1024 * 2);
  float* SUMF = (float*)take(128L * 2048 * 4);
  short* scat = (short*)take(128L * 2048 * 2);
  short* hh = (short*)take(128L * 1024 * 2);
  short* hf = (short*)take(128L * 1024 * 2);
  char* Areg = take(2 * R * 1024 * 2);  // FHID -> GHID
  char* Breg = take(2 * R * 1024 * 2);  // F12 -> CC12
  char* Creg = take(2 * R * 512 * 2);   // S12b -> E1|W1A|W2A
  char* Dreg = take(2 * R * 512 * 2);   // [S2T | S1T]
  (void)in_sizes; (void)n_in; (void)out_size;

  short* FHID = (short*)Areg;
  short* GHID = (short*)Areg;
  short* F12 = (short*)Breg;
  short* CC12 = (short*)Breg;
  short* S12b = (short*)Creg;
  float* E1 = (float*)Creg;
  short* W1A = (short*)(Creg + (long)Bh * 262144);
  short* W2A = W1A + (long)Bh * 65536;
  short* ST = (short*)Dreg;

  hipMemsetAsync(SUMF, 0, 128L * 2048 * 4, stream);

  CastArgs ca;
  ca.src[0] = f_w1; ca.dst[0] = (__hip_bfloat16*)Wf1; ca.n[0] = 524288;
  ca.src[1] = f_w2; ca.dst[1] = (__hip_bfloat16*)Wf2; ca.n[1] = 1048576;
  ca.src[2] = g_w1; ca.dst[2] = (__hip_bfloat16*)Wg1; ca.n[2] = 1048576;
  ca.src[3] = g_w2; ca.dst[3] = (__hip_bfloat16*)Wg2; ca.n[3] = 1048576;
  ca.src[4] = h_w1; ca.dst[4] = (__hip_bfloat16*)Wh1; ca.n[4] = 2097152;
  ca.src[5] = h_w2; ca.dst[5] = (__hip_bfloat16*)Wh2; ca.n[5] = 1048576;
  cast_many<<<dim3(2048, 6), 256, 0, stream>>>(ca);

  for (int c = 0; c < chunks; ++c) {
    const float* s1 = sent1 + (long)c * R * 512;
    const float* s2 = sent2 + (long)c * R * 512;
    float* SUMF_c = SUMF + (long)c * Bh * 2048;
    const int MT = (int)(2 * R / 128);

    prep_sent<<<dim3(16, 8, 2 * Bh), dim3(32, 8), 0, stream>>>(
        s1, s2, (__hip_bfloat16*)S12b, (__hip_bfloat16*)ST, Bh);

    // ---- attend MLP f (merged sides, M = 2R) ----
    gemm_nt<true, true, true, false, false><<<dim3(8, MT, 1), 256, 0, stream>>>(
        S12b, Wf1, f_b1, FHID, 512, 512, 512, 1024, 0, 0, 0, nullptr, nullptr, 0);
    gemm_nt<true, true, true, false, false><<<dim3(8, MT, 1), 256, 0, stream>>>(
        FHID, Wf2, f_b2, F12, 1024, 1024, 1024, 1024, 0, 0, 0, nullptr, nullptr, 0);

    // ---- e1 = F1 F2^T (batched fp32; overwrites S12b region) ----
    gemm_nt<false, false, false, false, false><<<dim3(2, 2, Bh), 256, 0, stream>>>(
        F12, F12 + R * 1024, nullptr, E1, 1024, 1024, 1024, 256, 256L * 1024,
        256L * 1024, 65536, nullptr, nullptr, 0);

    // ---- softmaxes ----
    softmax_rows<<<Bh * 256, 256, 0, stream>>>(E1, (__hip_bfloat16*)W1A);
    softmax_cols_f<<<dim3(4, Bh), 256, 0, stream>>>(E1, (__hip_bfloat16*)W2A);

    // ---- att (merged) + fused concat right-half fill ----
    gemm_nt<false, true, false, false, true><<<dim3(4, 2, 2 * Bh), 256, 0, stream>>>(
        W1A, ST, nullptr, CC12, 256, 256, 256, 1024, 65536, 131072, 262144,
        s1, s2, Bh);

    // ---- compare MLP g (merged); layer2 accumulates sum-over-L ----
    gemm_nt<true, true, true, false, false><<<dim3(8, MT, 1), 256, 0, stream>>>(
        CC12, Wg1, g_b1, GHID, 1024, 1024, 1024, 1024, 0, 0, 0, nullptr, nullptr, 0);
    gemm_nt<true, false, true, true, false><<<dim3(8, MT, 1), 256, 0, stream>>>(
        GHID, Wg2, g_b2, SUMF_c, 1024, 1024, 1024, 2048, 0, 0, Bh, nullptr, nullptr, 0);
  }

  // ---- aggregate MLP h + final linear ----
  cast_bf16<<<256, 256, 0, stream>>>(SUMF, (__hip_bfloat16*)scat, 262144);
  gemm_nt<true, true, true, false, false><<<dim3(8, 1, 1), 256, 0, stream>>>(
      scat, Wh1, h_b1, hh, 2048, 2048, 2048, 1024, 0, 0, 0, nullptr, nullptr, 0);
  gemm_nt<true, true, true, false, false><<<dim3(8, 1, 1), 256, 0, stream>>>(
      hh, Wh2, h_b2, hf, 1024, 1024, 1024, 1024, 0, 0, 0, nullptr, nullptr, 0);
  final_lin<<<128, 256, 0, stream>>>((__hip_bfloat16*)hf, fin_w, fin_b,
                                     (float*)d_out);
}

// Round 7
// 1043.408 us; speedup vs baseline: 1.4381x; 1.0637x over previous
//
#include <hip/hip_runtime.h>
#include <hip/hip_bf16.h>

// Decomposable attention, bf16-MFMA pipeline, chunked (Bh per side per chunk).
// R7: CONCAT epilogue rewritten as coalesced float4-read / ushort4-write tile
// sweep (R6's scalar scattered version made the att GEMM the top hotspot at
// 91us, MfmaUtil 3.4%). Everything else unchanged from R6.

using f32x4 = __attribute__((ext_vector_type(4))) float;
using s16x8 = __attribute__((ext_vector_type(8))) short;

__device__ __forceinline__ void gload_lds16(const short* g, short* l) {
  __builtin_amdgcn_global_load_lds(
      (const __attribute__((address_space(1))) unsigned int*)g,
      (__attribute__((address_space(3))) unsigned int*)l, 16, 0, 0);
}

// ---------------- GEMM: C[M,N] = A[M,K] * B[N,K]^T (+bias, relu) ----------------
// grid = (N/128, M/128, batch), block = 256.
// LDS XOR swizzle: row r chunk c at slot c ^ ((r>>1)&3) — 0 bank conflicts (R5).
// SUML: row-sum per 256-row batch into float Cv; sC = split.
// CONCAT: att epilogue also fills right concat half from fp32 sent (cs1/cs2),
// as a separate fully-coalesced 128x128 tile sweep.
template <bool RELU, bool OUT_BF16, bool HAS_BIAS, bool SUML, bool CONCAT>
__global__ __launch_bounds__(256, 4) void gemm_nt(
    const short* __restrict__ A, const short* __restrict__ B,
    const float* __restrict__ bias, void* __restrict__ Cv, int K, int lda,
    int ldb, int ldc, long sA, long sB, long sC, const float* __restrict__ cs1,
    const float* __restrict__ cs2, int cBh) {
  __shared__ __align__(16) short As[128 * 32];
  __shared__ __align__(16) short Bs[128 * 32];
  const int t = threadIdx.x;
  const int lane = t & 63;
  const int wave = t >> 6;

  // XCD-aware swizzle (flat%8 ~ XCD): contiguous tile range per XCD.
  unsigned flat = (blockIdx.z * gridDim.y + blockIdx.y) * gridDim.x + blockIdx.x;
  const unsigned total = gridDim.x * gridDim.y * gridDim.z;
  unsigned bx = blockIdx.x, by = blockIdx.y, bz = blockIdx.z;
  if ((total & 7u) == 0) {
    unsigned nf = (flat & 7u) * (total >> 3) + (flat >> 3);
    bx = nf % gridDim.x;
    unsigned rest = nf / gridDim.x;
    by = rest % gridDim.y;
    bz = rest / gridDim.y;
  }
  const int m0 = by * 128;
  const int n0 = bx * 128;
  const long zb = bz;

  // staging: thread t fills LDS slot t (16B); fetches swizzled global chunk.
  const int swz = ((t & 3) ^ ((t >> 3) & 3)) * 8;
  const short* ag0 = A + zb * sA + (long)(m0 + (t >> 2)) * lda + swz;
  const short* ag1 = ag0 + (long)64 * lda;
  const short* bg0 = B + zb * sB + (long)(n0 + (t >> 2)) * ldb + swz;
  const short* bg1 = bg0 + (long)64 * ldb;
  short* AsW = As + wave * 512;
  short* BsW = Bs + wave * 512;

  const int fr = lane & 15;
  const int kq = lane >> 4;
  int aoff[4], boff[4];
#pragma unroll
  for (int i = 0; i < 4; ++i) {
    const int ra = (wave >> 1) * 64 + i * 16 + fr;
    const int rb = (wave & 1) * 64 + i * 16 + fr;
    aoff[i] = ra * 32 + (kq ^ ((ra >> 1) & 3)) * 8;
    boff[i] = rb * 32 + (kq ^ ((rb >> 1) & 3)) * 8;
  }

  f32x4 acc[4][4] = {};

  for (int it = K >> 5; it > 0; --it) {
    gload_lds16(ag0, AsW);
    gload_lds16(ag1, AsW + 2048);
    gload_lds16(bg0, BsW);
    gload_lds16(bg1, BsW + 2048);
    ag0 += 32; ag1 += 32; bg0 += 32; bg1 += 32;
    __syncthreads();
    s16x8 af[4], bfv[4];
#pragma unroll
    for (int i = 0; i < 4; ++i) af[i] = *(const s16x8*)(As + aoff[i]);
#pragma unroll
    for (int j = 0; j < 4; ++j) bfv[j] = *(const s16x8*)(Bs + boff[j]);
#pragma unroll
    for (int i = 0; i < 4; ++i)
#pragma unroll
      for (int j = 0; j < 4; ++j)
        acc[i][j] = __builtin_amdgcn_mfma_f32_16x16x32_bf16(af[i], bfv[j],
                                                            acc[i][j], 0, 0, 0);
    __syncthreads();
  }

  // C/D layout: col = lane&15, row = (lane>>4)*4 + reg  [m89/m91-verified]
  const int ccol = lane & 15;
  const int crow = (lane >> 4) * 4;

  if constexpr (SUML) {
    __shared__ float ssum[128];
    if (t < 128) ssum[t] = 0.f;
    __syncthreads();
#pragma unroll
    for (int j = 0; j < 4; ++j) {
      const int lcol = (wave & 1) * 64 + j * 16 + ccol;
      float bj = HAS_BIAS ? bias[n0 + lcol] : 0.f;
      float part = 0.f;
#pragma unroll
      for (int i = 0; i < 4; ++i)
#pragma unroll
        for (int r = 0; r < 4; ++r) {
          float x = acc[i][j][r] + bj;
          if (RELU) x = fmaxf(x, 0.f);
          part += x;
        }
      atomicAdd(&ssum[lcol], part);
    }
    __syncthreads();
    if (t < 128) {
      const int split = (int)sC;
      int rb2 = m0 >> 8;
      const int side = rb2 >= split;
      rb2 -= side * split;
      atomicAdd((float*)Cv + (long)rb2 * ldc + side * (ldc >> 1) + n0 + t,
                ssum[t]);
    }
  } else {
#pragma unroll
    for (int j = 0; j < 4; ++j) {
      const int col = n0 + (wave & 1) * 64 + j * 16 + ccol;
      float bj = 0.f;
      if (HAS_BIAS) bj = bias[col];
#pragma unroll
      for (int i = 0; i < 4; ++i) {
        const int row0 = m0 + (wave >> 1) * 64 + i * 16 + crow;
#pragma unroll
        for (int r = 0; r < 4; ++r) {
          float x = acc[i][j][r] + bj;
          if (RELU) x = fmaxf(x, 0.f);
          const long idx = (long)(row0 + r) * ldc + col + zb * sC;
          if (OUT_BF16)
            ((__hip_bfloat16*)Cv)[idx] = __float2bfloat16(x);
          else
            ((float*)Cv)[idx] = x;
        }
      }
    }
    if constexpr (CONCAT) {
      // Coalesced concat fill: this block's 128x128 fp32 tile of sent ->
      // bf16 right half of CC. float4 reads, ushort4 writes.
      const int side = (int)(zb >= (long)cBh);
      const int bb = (int)zb - side * cBh;
      const float* csrc = side ? cs2 : cs1;
      const long crowbase = (long)bb * 256;
      __hip_bfloat16* Cb = (__hip_bfloat16*)Cv + zb * sC + 512 + n0;
#pragma unroll
      for (int k = 0; k < 16; ++k) {
        const int idx = k * 256 + t;  // 0..4095
        const int r = idx >> 5;       // row 0..127
        const int q = idx & 31;       // float4 col 0..31
        const float4 v =
            *(const float4*)(csrc + (crowbase + m0 + r) * 512 + n0 + q * 4);
        union {
          ushort4 u;
          __hip_bfloat16 h[4];
        } pk;
        pk.h[0] = __float2bfloat16(v.x);
        pk.h[1] = __float2bfloat16(v.y);
        pk.h[2] = __float2bfloat16(v.z);
        pk.h[3] = __float2bfloat16(v.w);
        *(ushort4*)(Cb + (long)(m0 + r) * ldc + q * 4) = pk.u;
      }
    }
  }
}

// ---------------- helpers ----------------
struct CastArgs {
  const float* src[6];
  __hip_bfloat16* dst[6];
  long n[6];
};
__global__ void cast_many(CastArgs a) {
  const int w = blockIdx.y;
  long i = ((long)blockIdx.x * blockDim.x + threadIdx.x) * 4;
  if (i >= a.n[w]) return;
  float4 v = *(const float4*)(a.src[w] + i);
  __hip_bfloat16* o = a.dst[w] + i;
  o[0] = __float2bfloat16(v.x);
  o[1] = __float2bfloat16(v.y);
  o[2] = __float2bfloat16(v.z);
  o[3] = __float2bfloat16(v.w);
}

__global__ void cast_bf16(const float* __restrict__ in,
                          __hip_bfloat16* __restrict__ out, long n) {
  long i = ((long)blockIdx.x * blockDim.x + threadIdx.x) * 4;
  if (i >= n) return;
  float4 v = *(const float4*)(in + i);
  out[i + 0] = __float2bfloat16(v.x);
  out[i + 1] = __float2bfloat16(v.y);
  out[i + 2] = __float2bfloat16(v.z);
  out[i + 3] = __float2bfloat16(v.w);
}

// Fused sent prep: fp32 sent -> row-major bf16 (S12b) AND transposed bf16
// (ST = [S2T|S1T]). z < Bh -> sent1, else sent2.
__global__ void prep_sent(const float* __restrict__ s1,
                          const float* __restrict__ s2,
                          __hip_bfloat16* __restrict__ S12b,
                          __hip_bfloat16* __restrict__ STbase, int Bh) {
  __shared__ float tile[32][33];
  const int z = blockIdx.z;
  const int e0 = blockIdx.x * 32;
  const int l0 = blockIdx.y * 32;
  const int side = z >= Bh;
  const int b = z - side * Bh;
  const float* ib = (side ? s2 : s1) + (long)b * 131072;
  __hip_bfloat16* on = S12b + (long)z * 131072;
  __hip_bfloat16* ot = STbase + (long)(side ? b : (Bh + b)) * 131072;
  const int tx = threadIdx.x, ty = threadIdx.y;
#pragma unroll
  for (int k = 0; k < 4; ++k) {
    const int l = l0 + ty + 8 * k;
    const float v = ib[(long)l * 512 + e0 + tx];
    on[(long)l * 512 + e0 + tx] = __float2bfloat16(v);
    tile[ty + 8 * k][tx] = v;
  }
  __syncthreads();
#pragma unroll
  for (int k = 0; k < 4; ++k)
    ot[(long)(e0 + ty + 8 * k) * 256 + l0 + tx] =
        __float2bfloat16(tile[tx][ty + 8 * k]);
}

// row softmax over 256 cols: E fp32 [rows][256] -> W bf16 (coalesced)
__global__ void softmax_rows(const float* __restrict__ E,
                             __hip_bfloat16* __restrict__ W) {
  const long row = blockIdx.x;
  const int t = threadIdx.x;
  const float x = E[row * 256 + t];
  float m = x;
  for (int o = 32; o > 0; o >>= 1) m = fmaxf(m, __shfl_xor(m, o));
  __shared__ float red[4];
  if ((t & 63) == 0) red[t >> 6] = m;
  __syncthreads();
  m = fmaxf(fmaxf(red[0], red[1]), fmaxf(red[2], red[3]));
  const float pr = __expf(x - m);
  float s = pr;
  for (int o = 32; o > 0; o >>= 1) s += __shfl_xor(s, o);
  __shared__ float red2[4];
  if ((t & 63) == 0) red2[t >> 6] = s;
  __syncthreads();
  s = red2[0] + red2[1] + red2[2] + red2[3];
  W[row * 256 + t] = __float2bfloat16(pr / s);
}

// Fused column softmax: strip in LDS, stats, transposed coalesced write.
__global__ __launch_bounds__(256) void softmax_cols_f(
    const float* __restrict__ E, __hip_bfloat16* __restrict__ W) {
  __shared__ float tile[256][65];
  __shared__ float mred[4][64], sred[4][64];
  const int b = blockIdx.y;
  const int j0 = blockIdx.x * 64;
  const int t = threadIdx.x;
  const int jl = t & 63, s = t >> 6;
  const float* Eb = E + (long)b * 65536 + j0;
#pragma unroll
  for (int k = 0; k < 64; ++k) {
    const int i = k * 4 + s;
    tile[i][jl] = Eb[(long)i * 256 + jl];
  }
  __syncthreads();
  float m = -3.4e38f;
#pragma unroll 8
  for (int r = 0; r < 64; ++r) m = fmaxf(m, tile[s * 64 + r][jl]);
  mred[s][jl] = m;
  __syncthreads();
  m = fmaxf(fmaxf(mred[0][jl], mred[1][jl]), fmaxf(mred[2][jl], mred[3][jl]));
  float sum = 0.f;
#pragma unroll 8
  for (int r = 0; r < 64; ++r) sum += __expf(tile[s * 64 + r][jl] - m);
  sred[s][jl] = sum;
  __syncthreads();
  const int jw = t >> 2;
  const int ib = t & 3;
  const float mj = fmaxf(fmaxf(mred[0][jw], mred[1][jw]),
                         fmaxf(mred[2][jw], mred[3][jw]));
  const float isj =
      1.0f / (sred[0][jw] + sred[1][jw] + sred[2][jw] + sred[3][jw]);
  __hip_bfloat16* Wb = W + (long)b * 65536 + (long)(j0 + jw) * 256 + ib * 64;
#pragma unroll 8
  for (int r = 0; r < 64; ++r)
    Wb[r] = __float2bfloat16(__expf(tile[ib * 64 + r][jw] - mj) * isj);
}

// out[b][o] = sum_h h2[b][h]*fin_w[o][h] + fin_b[o]
__global__ void final_lin(const __hip_bfloat16* __restrict__ h2,
                          const float* __restrict__ w,
                          const float* __restrict__ bs,
                          float* __restrict__ out) {
  const int b = blockIdx.x;
  const int t = threadIdx.x;
  float p0 = 0.f, p1 = 0.f, p2 = 0.f;
  for (int k = t; k < 1024; k += 256) {
    const float x = __bfloat162float(h2[(long)b * 1024 + k]);
    p0 += x * w[k];
    p1 += x * w[1024 + k];
    p2 += x * w[2048 + k];
  }
  for (int o = 32; o > 0; o >>= 1) {
    p0 += __shfl_xor(p0, o);
    p1 += __shfl_xor(p1, o);
    p2 += __shfl_xor(p2, o);
  }
  __shared__ float r[4][3];
  if ((t & 63) == 0) {
    r[t >> 6][0] = p0;
    r[t >> 6][1] = p1;
    r[t >> 6][2] = p2;
  }
  __syncthreads();
  if (t < 3)
    out[b * 3 + t] = r[0][t] + r[1][t] + r[2][t] + r[3][t] + bs[t];
}

extern "C" void kernel_launch(void* const* d_in, const int* in_sizes, int n_in,
                              void* d_out, int out_size, void* d_ws,
                              size_t ws_size, hipStream_t stream) {
  const float* sent1 = (const float*)d_in[0];
  const float* sent2 = (const float*)d_in[1];
  const float* f_w1 = (const float*)d_in[2];
  const float* f_b1 = (const float*)d_in[3];
  const float* f_w2 = (const float*)d_in[4];
  const float* f_b2 = (const float*)d_in[5];
  const float* g_w1 = (const float*)d_in[6];
  const float* g_b1 = (const float*)d_in[7];
  const float* g_w2 = (const float*)d_in[8];
  const float* g_b2 = (const float*)d_in[9];
  const float* h_w1 = (const float*)d_in[10];
  const float* h_b1 = (const float*)d_in[11];
  const float* h_w2 = (const float*)d_in[12];
  const float* h_b2 = (const float*)d_in[13];
  const float* fin_w = (const float*)d_in[14];
  const float* fin_b = (const float*)d_in[15];

  char* p = (char*)d_ws;
  auto take = [&](size_t n) {
    char* r = p;
    p += (n + 255) & ~(size_t)255;
    return r;
  };
  const int Bh = (ws_size >= (size_t)220 * 1024 * 1024) ? 64 : 32;
  const int chunks = 128 / Bh;
  const long R = (long)Bh * 256;

  short* Wf1 = (short*)take(1024L * 512 * 2);
  short* Wf2 = (short*)take(1024L * 1024 * 2);
  short* Wg1 = (short*)take(1024L * 1024 * 2);
  short* Wg2 = (short*)take(1024L * 1024 * 2);
  short* Wh1 = (short*)take(1024L * 2048 * 2);
  short* Wh2 = (short*)take(1024L * 1024 * 2);
  float* SUMF = (float*)take(128L * 2048 * 4);
  short* scat = (short*)take(128L * 2048 * 2);
  short* hh = (short*)take(128L * 1024 * 2);
  short* hf = (short*)take(128L * 1024 * 2);
  char* Areg = take(2 * R * 1024 * 2);  // FHID -> GHID
  char* Breg = take(2 * R * 1024 * 2);  // F12 -> CC12
  char* Creg = take(2 * R * 512 * 2);   // S12b -> E1|W1A|W2A
  char* Dreg = take(2 * R * 512 * 2);   // [S2T | S1T]
  (void)in_sizes; (void)n_in; (void)out_size;

  short* FHID = (short*)Areg;
  short* GHID = (short*)Areg;
  short* F12 = (short*)Breg;
  short* CC12 = (short*)Breg;
  short* S12b = (short*)Creg;
  float* E1 = (float*)Creg;
  short* W1A = (short*)(Creg + (long)Bh * 262144);
  short* W2A = W1A + (long)Bh * 65536;
  short* ST = (short*)Dreg;

  hipMemsetAsync(SUMF, 0, 128L * 2048 * 4, stream);

  CastArgs ca;
  ca.src[0] = f_w1; ca.dst[0] = (__hip_bfloat16*)Wf1; ca.n[0] = 524288;
  ca.src[1] = f_w2; ca.dst[1] = (__hip_bfloat16*)Wf2; ca.n[1] = 1048576;
  ca.src[2] = g_w1; ca.dst[2] = (__hip_bfloat16*)Wg1; ca.n[2] = 1048576;
  ca.src[3] = g_w2; ca.dst[3] = (__hip_bfloat16*)Wg2; ca.n[3] = 1048576;
  ca.src[4] = h_w1; ca.dst[4] = (__hip_bfloat16*)Wh1; ca.n[4] = 2097152;
  ca.src[5] = h_w2; ca.dst[5] = (__hip_bfloat16*)Wh2; ca.n[5] = 1048576;
  cast_many<<<dim3(2048, 6), 256, 0, stream>>>(ca);

  for (int c = 0; c < chunks; ++c) {
    const float* s1 = sent1 + (long)c * R * 512;
    const float* s2 = sent2 + (long)c * R * 512;
    float* SUMF_c = SUMF + (long)c * Bh * 2048;
    const int MT = (int)(2 * R / 128);

    prep_sent<<<dim3(16, 8, 2 * Bh), dim3(32, 8), 0, stream>>>(
        s1, s2, (__hip_bfloat16*)S12b, (__hip_bfloat16*)ST, Bh);

    // ---- attend MLP f (merged sides, M = 2R) ----
    gemm_nt<true, true, true, false, false><<<dim3(8, MT, 1), 256, 0, stream>>>(
        S12b, Wf1, f_b1, FHID, 512, 512, 512, 1024, 0, 0, 0, nullptr, nullptr, 0);
    gemm_nt<true, true, true, false, false><<<dim3(8, MT, 1), 256, 0, stream>>>(
        FHID, Wf2, f_b2, F12, 1024, 1024, 1024, 1024, 0, 0, 0, nullptr, nullptr, 0);

    // ---- e1 = F1 F2^T (batched fp32; overwrites S12b region) ----
    gemm_nt<false, false, false, false, false><<<dim3(2, 2, Bh), 256, 0, stream>>>(
        F12, F12 + R * 1024, nullptr, E1, 1024, 1024, 1024, 256, 256L * 1024,
        256L * 1024, 65536, nullptr, nullptr, 0);

    // ---- softmaxes ----
    softmax_rows<<<Bh * 256, 256, 0, stream>>>(E1, (__hip_bfloat16*)W1A);
    softmax_cols_f<<<dim3(4, Bh), 256, 0, stream>>>(E1, (__hip_bfloat16*)W2A);

    // ---- att (merged) + fused coalesced concat right-half fill ----
    gemm_nt<false, true, false, false, true><<<dim3(4, 2, 2 * Bh), 256, 0, stream>>>(
        W1A, ST, nullptr, CC12, 256, 256, 256, 1024, 65536, 131072, 262144,
        s1, s2, Bh);

    // ---- compare MLP g (merged); layer2 accumulates sum-over-L ----
    gemm_nt<true, true, true, false, false><<<dim3(8, MT, 1), 256, 0, stream>>>(
        CC12, Wg1, g_b1, GHID, 1024, 1024, 1024, 1024, 0, 0, 0, nullptr, nullptr, 0);
    gemm_nt<true, false, true, true, false><<<dim3(8, MT, 1), 256, 0, stream>>>(
        GHID, Wg2, g_b2, SUMF_c, 1024, 1024, 1024, 2048, 0, 0, Bh, nullptr, nullptr, 0);
  }

  // ---- aggregate MLP h + final linear ----
  cast_bf16<<<256, 256, 0, stream>>>(SUMF, (__hip_bfloat16*)scat, 262144);
  gemm_nt<true, true, true, false, false><<<dim3(8, 1, 1), 256, 0, stream>>>(
      scat, Wh1, h_b1, hh, 2048, 2048, 2048, 1024, 0, 0, 0, nullptr, nullptr, 0);
  gemm_nt<true, true, true, false, false><<<dim3(8, 1, 1), 256, 0, stream>>>(
      hh, Wh2, h_b2, hf, 1024, 1024, 1024, 1024, 0, 0, 0, nullptr, nullptr, 0);
  final_lin<<<128, 256, 0, stream>>>((__hip_bfloat16*)hf, fin_w, fin_b,
                                     (float*)d_out);
}

// Round 8
// 922.385 us; speedup vs baseline: 1.6268x; 1.1312x over previous
//
#include <hip/hip_runtime.h>
#include <hip/hip_bf16.h>

// Decomposable attention, bf16-MFMA pipeline, chunked (Bh per side per chunk).
// R8: BK=64 K-loop (halves the number of vmcnt(0)+barrier drains per GEMM;
// LDS 33 KB keeps 4 blocks/CU, unlike m132's BK=128). XOR swizzle extended to
// 8 chunks/row: slot = chunk ^ (row&7); k-upper fragment read = offset ^ 32.

using f32x4 = __attribute__((ext_vector_type(4))) float;
using s16x8 = __attribute__((ext_vector_type(8))) short;

__device__ __forceinline__ void gload_lds16(const short* g, short* l) {
  __builtin_amdgcn_global_load_lds(
      (const __attribute__((address_space(1))) unsigned int*)g,
      (__attribute__((address_space(3))) unsigned int*)l, 16, 0, 0);
}

// ---------------- GEMM: C[M,N] = A[M,K] * B[N,K]^T (+bias, relu) ----------------
// grid = (N/128, M/128, batch), block = 256. K % 64 == 0.
// LDS: [128][64] bf16 per operand; row r chunk c (16B) at slot c ^ (r&7).
// SUML: row-sum per 256-row batch into float Cv; sC = split.
// CONCAT: att epilogue fills right concat half (coalesced tile sweep).
template <bool RELU, bool OUT_BF16, bool HAS_BIAS, bool SUML, bool CONCAT>
__global__ __launch_bounds__(256, 4) void gemm_nt(
    const short* __restrict__ A, const short* __restrict__ B,
    const float* __restrict__ bias, void* __restrict__ Cv, int K, int lda,
    int ldb, int ldc, long sA, long sB, long sC, const float* __restrict__ cs1,
    const float* __restrict__ cs2, int cBh) {
  __shared__ __align__(16) short As[128 * 64];
  __shared__ __align__(16) short Bs[128 * 64];
  const int t = threadIdx.x;
  const int lane = t & 63;
  const int wave = t >> 6;

  // XCD-aware swizzle (flat%8 ~ XCD): contiguous tile range per XCD.
  unsigned flat = (blockIdx.z * gridDim.y + blockIdx.y) * gridDim.x + blockIdx.x;
  const unsigned total = gridDim.x * gridDim.y * gridDim.z;
  unsigned bx = blockIdx.x, by = blockIdx.y, bz = blockIdx.z;
  if ((total & 7u) == 0) {
    unsigned nf = (flat & 7u) * (total >> 3) + (flat >> 3);
    bx = nf % gridDim.x;
    unsigned rest = nf / gridDim.x;
    by = rest % gridDim.y;
    bz = rest / gridDim.y;
  }
  const int m0 = by * 128;
  const int n0 = bx * 128;
  const long zb = bz;

  // staging: issue q covers rows q*32..q*32+31; thread t -> row q*32+(t>>3),
  // LDS slot (t&7), fetching global chunk (t&7)^((t>>3)&7).
  const int srow = t >> 3;
  const int schunk = ((t & 7) ^ (srow & 7)) * 8;
  const short* ag = A + zb * sA + (long)(m0 + srow) * lda + schunk;
  const short* bg = B + zb * sB + (long)(n0 + srow) * ldb + schunk;
  const long a32 = (long)32 * lda, b32 = (long)32 * ldb;
  short* AsW = As + wave * 512;  // + q*2048 shorts per issue
  short* BsW = Bs + wave * 512;

  const int fr = lane & 15;
  const int kq = lane >> 4;  // 16B chunk (k1=0 half) 0..3
  int aoff[4], boff[4];
#pragma unroll
  for (int i = 0; i < 4; ++i) {
    const int ra = (wave >> 1) * 64 + i * 16 + fr;
    const int rb = (wave & 1) * 64 + i * 16 + fr;
    aoff[i] = ra * 64 + ((kq ^ (ra & 7)) * 8);
    boff[i] = rb * 64 + ((kq ^ (rb & 7)) * 8);
  }

  f32x4 acc[4][4] = {};

  for (int it = K >> 6; it > 0; --it) {
    gload_lds16(ag, AsW);
    gload_lds16(ag + a32, AsW + 2048);
    gload_lds16(ag + 2 * a32, AsW + 4096);
    gload_lds16(ag + 3 * a32, AsW + 6144);
    gload_lds16(bg, BsW);
    gload_lds16(bg + b32, BsW + 2048);
    gload_lds16(bg + 2 * b32, BsW + 4096);
    gload_lds16(bg + 3 * b32, BsW + 6144);
    ag += 64;
    bg += 64;
    __syncthreads();
#pragma unroll
    for (int kk = 0; kk < 2; ++kk) {
      const int x = kk * 32;  // offset^32 flips chunk bit2 (k-upper half)
      s16x8 af[4], bfv[4];
#pragma unroll
      for (int i = 0; i < 4; ++i) af[i] = *(const s16x8*)(As + (aoff[i] ^ x));
#pragma unroll
      for (int j = 0; j < 4; ++j) bfv[j] = *(const s16x8*)(Bs + (boff[j] ^ x));
#pragma unroll
      for (int i = 0; i < 4; ++i)
#pragma unroll
        for (int j = 0; j < 4; ++j)
          acc[i][j] = __builtin_amdgcn_mfma_f32_16x16x32_bf16(
              af[i], bfv[j], acc[i][j], 0, 0, 0);
    }
    __syncthreads();
  }

  // C/D layout: col = lane&15, row = (lane>>4)*4 + reg  [m89/m91-verified]
  const int ccol = lane & 15;
  const int crow = (lane >> 4) * 4;

  if constexpr (SUML) {
    __shared__ float ssum[128];
    if (t < 128) ssum[t] = 0.f;
    __syncthreads();
#pragma unroll
    for (int j = 0; j < 4; ++j) {
      const int lcol = (wave & 1) * 64 + j * 16 + ccol;
      float bj = HAS_BIAS ? bias[n0 + lcol] : 0.f;
      float part = 0.f;
#pragma unroll
      for (int i = 0; i < 4; ++i)
#pragma unroll
        for (int r = 0; r < 4; ++r) {
          float x = acc[i][j][r] + bj;
          if (RELU) x = fmaxf(x, 0.f);
          part += x;
        }
      atomicAdd(&ssum[lcol], part);
    }
    __syncthreads();
    if (t < 128) {
      const int split = (int)sC;
      int rb2 = m0 >> 8;
      const int side = rb2 >= split;
      rb2 -= side * split;
      atomicAdd((float*)Cv + (long)rb2 * ldc + side * (ldc >> 1) + n0 + t,
                ssum[t]);
    }
  } else {
#pragma unroll
    for (int j = 0; j < 4; ++j) {
      const int col = n0 + (wave & 1) * 64 + j * 16 + ccol;
      float bj = 0.f;
      if (HAS_BIAS) bj = bias[col];
#pragma unroll
      for (int i = 0; i < 4; ++i) {
        const int row0 = m0 + (wave >> 1) * 64 + i * 16 + crow;
#pragma unroll
        for (int r = 0; r < 4; ++r) {
          float x = acc[i][j][r] + bj;
          if (RELU) x = fmaxf(x, 0.f);
          const long idx = (long)(row0 + r) * ldc + col + zb * sC;
          if (OUT_BF16)
            ((__hip_bfloat16*)Cv)[idx] = __float2bfloat16(x);
          else
            ((float*)Cv)[idx] = x;
        }
      }
    }
    if constexpr (CONCAT) {
      // Coalesced concat fill: this block's 128x128 fp32 tile of sent ->
      // bf16 right half of CC. float4 reads, ushort4 writes.
      const int side = (int)(zb >= (long)cBh);
      const int bb = (int)zb - side * cBh;
      const float* csrc = side ? cs2 : cs1;
      const long crowbase = (long)bb * 256;
      __hip_bfloat16* Cb = (__hip_bfloat16*)Cv + zb * sC + 512 + n0;
#pragma unroll
      for (int k = 0; k < 16; ++k) {
        const int idx = k * 256 + t;  // 0..4095
        const int r = idx >> 5;       // row 0..127
        const int q = idx & 31;       // float4 col 0..31
        const float4 v =
            *(const float4*)(csrc + (crowbase + m0 + r) * 512 + n0 + q * 4);
        union {
          ushort4 u;
          __hip_bfloat16 h[4];
        } pk;
        pk.h[0] = __float2bfloat16(v.x);
        pk.h[1] = __float2bfloat16(v.y);
        pk.h[2] = __float2bfloat16(v.z);
        pk.h[3] = __float2bfloat16(v.w);
        *(ushort4*)(Cb + (long)(m0 + r) * ldc + q * 4) = pk.u;
      }
    }
  }
}

// ---------------- helpers ----------------
struct CastArgs {
  const float* src[6];
  __hip_bfloat16* dst[6];
  long n[6];
};
__global__ void cast_many(CastArgs a) {
  const int w = blockIdx.y;
  long i = ((long)blockIdx.x * blockDim.x + threadIdx.x) * 4;
  if (i >= a.n[w]) return;
  float4 v = *(const float4*)(a.src[w] + i);
  __hip_bfloat16* o = a.dst[w] + i;
  o[0] = __float2bfloat16(v.x);
  o[1] = __float2bfloat16(v.y);
  o[2] = __float2bfloat16(v.z);
  o[3] = __float2bfloat16(v.w);
}

__global__ void cast_bf16(const float* __restrict__ in,
                          __hip_bfloat16* __restrict__ out, long n) {
  long i = ((long)blockIdx.x * blockDim.x + threadIdx.x) * 4;
  if (i >= n) return;
  float4 v = *(const float4*)(in + i);
  out[i + 0] = __float2bfloat16(v.x);
  out[i + 1] = __float2bfloat16(v.y);
  out[i + 2] = __float2bfloat16(v.z);
  out[i + 3] = __float2bfloat16(v.w);
}

// Fused sent prep: fp32 sent -> row-major bf16 (S12b) AND transposed bf16
// (ST = [S2T|S1T]). z < Bh -> sent1, else sent2.
__global__ void prep_sent(const float* __restrict__ s1,
                          const float* __restrict__ s2,
                          __hip_bfloat16* __restrict__ S12b,
                          __hip_bfloat16* __restrict__ STbase, int Bh) {
  __shared__ float tile[32][33];
  const int z = blockIdx.z;
  const int e0 = blockIdx.x * 32;
  const int l0 = blockIdx.y * 32;
  const int side = z >= Bh;
  const int b = z - side * Bh;
  const float* ib = (side ? s2 : s1) + (long)b * 131072;
  __hip_bfloat16* on = S12b + (long)z * 131072;
  __hip_bfloat16* ot = STbase + (long)(side ? b : (Bh + b)) * 131072;
  const int tx = threadIdx.x, ty = threadIdx.y;
#pragma unroll
  for (int k = 0; k < 4; ++k) {
    const int l = l0 + ty + 8 * k;
    const float v = ib[(long)l * 512 + e0 + tx];
    on[(long)l * 512 + e0 + tx] = __float2bfloat16(v);
    tile[ty + 8 * k][tx] = v;
  }
  __syncthreads();
#pragma unroll
  for (int k = 0; k < 4; ++k)
    ot[(long)(e0 + ty + 8 * k) * 256 + l0 + tx] =
        __float2bfloat16(tile[tx][ty + 8 * k]);
}

// row softmax over 256 cols: E fp32 [rows][256] -> W bf16 (coalesced)
__global__ void softmax_rows(const float* __restrict__ E,
                             __hip_bfloat16* __restrict__ W) {
  const long row = blockIdx.x;
  const int t = threadIdx.x;
  const float x = E[row * 256 + t];
  float m = x;
  for (int o = 32; o > 0; o >>= 1) m = fmaxf(m, __shfl_xor(m, o));
  __shared__ float red[4];
  if ((t & 63) == 0) red[t >> 6] = m;
  __syncthreads();
  m = fmaxf(fmaxf(red[0], red[1]), fmaxf(red[2], red[3]));
  const float pr = __expf(x - m);
  float s = pr;
  for (int o = 32; o > 0; o >>= 1) s += __shfl_xor(s, o);
  __shared__ float red2[4];
  if ((t & 63) == 0) red2[t >> 6] = s;
  __syncthreads();
  s = red2[0] + red2[1] + red2[2] + red2[3];
  W[row * 256 + t] = __float2bfloat16(pr / s);
}

// Fused column softmax: strip in LDS, stats, transposed coalesced write.
__global__ __launch_bounds__(256) void softmax_cols_f(
    const float* __restrict__ E, __hip_bfloat16* __restrict__ W) {
  __shared__ float tile[256][65];
  __shared__ float mred[4][64], sred[4][64];
  const int b = blockIdx.y;
  const int j0 = blockIdx.x * 64;
  const int t = threadIdx.x;
  const int jl = t & 63, s = t >> 6;
  const float* Eb = E + (long)b * 65536 + j0;
#pragma unroll
  for (int k = 0; k < 64; ++k) {
    const int i = k * 4 + s;
    tile[i][jl] = Eb[(long)i * 256 + jl];
  }
  __syncthreads();
  float m = -3.4e38f;
#pragma unroll 8
  for (int r = 0; r < 64; ++r) m = fmaxf(m, tile[s * 64 + r][jl]);
  mred[s][jl] = m;
  __syncthreads();
  m = fmaxf(fmaxf(mred[0][jl], mred[1][jl]), fmaxf(mred[2][jl], mred[3][jl]));
  float sum = 0.f;
#pragma unroll 8
  for (int r = 0; r < 64; ++r) sum += __expf(tile[s * 64 + r][jl] - m);
  sred[s][jl] = sum;
  __syncthreads();
  const int jw = t >> 2;
  const int ib = t & 3;
  const float mj = fmaxf(fmaxf(mred[0][jw], mred[1][jw]),
                         fmaxf(mred[2][jw], mred[3][jw]));
  const float isj =
      1.0f / (sred[0][jw] + sred[1][jw] + sred[2][jw] + sred[3][jw]);
  __hip_bfloat16* Wb = W + (long)b * 65536 + (long)(j0 + jw) * 256 + ib * 64;
#pragma unroll 8
  for (int r = 0; r < 64; ++r)
    Wb[r] = __float2bfloat16(__expf(tile[ib * 64 + r][jw] - mj) * isj);
}

// out[b][o] = sum_h h2[b][h]*fin_w[o][h] + fin_b[o]
__global__ void final_lin(const __hip_bfloat16* __restrict__ h2,
                          const float* __restrict__ w,
                          const float* __restrict__ bs,
                          float* __restrict__ out) {
  const int b = blockIdx.x;
  const int t = threadIdx.x;
  float p0 = 0.f, p1 = 0.f, p2 = 0.f;
  for (int k = t; k < 1024; k += 256) {
    const float x = __bfloat162float(h2[(long)b * 1024 + k]);
    p0 += x * w[k];
    p1 += x * w[1024 + k];
    p2 += x * w[2048 + k];
  }
  for (int o = 32; o > 0; o >>= 1) {
    p0 += __shfl_xor(p0, o);
    p1 += __shfl_xor(p1, o);
    p2 += __shfl_xor(p2, o);
  }
  __shared__ float r[4][3];
  if ((t & 63) == 0) {
    r[t >> 6][0] = p0;
    r[t >> 6][1] = p1;
    r[t >> 6][2] = p2;
  }
  __syncthreads();
  if (t < 3)
    out[b * 3 + t] = r[0][t] + r[1][t] + r[2][t] + r[3][t] + bs[t];
}

extern "C" void kernel_launch(void* const* d_in, const int* in_sizes, int n_in,
                              void* d_out, int out_size, void* d_ws,
                              size_t ws_size, hipStream_t stream) {
  const float* sent1 = (const float*)d_in[0];
  const float* sent2 = (const float*)d_in[1];
  const float* f_w1 = (const float*)d_in[2];
  const float* f_b1 = (const float*)d_in[3];
  const float* f_w2 = (const float*)d_in[4];
  const float* f_b2 = (const float*)d_in[5];
  const float* g_w1 = (const float*)d_in[6];
  const float* g_b1 = (const float*)d_in[7];
  const float* g_w2 = (const float*)d_in[8];
  const float* g_b2 = (const float*)d_in[9];
  const float* h_w1 = (const float*)d_in[10];
  const float* h_b1 = (const float*)d_in[11];
  const float* h_w2 = (const float*)d_in[12];
  const float* h_b2 = (const float*)d_in[13];
  const float* fin_w = (const float*)d_in[14];
  const float* fin_b = (const float*)d_in[15];

  char* p = (char*)d_ws;
  auto take = [&](size_t n) {
    char* r = p;
    p += (n + 255) & ~(size_t)255;
    return r;
  };
  const int Bh = (ws_size >= (size_t)220 * 1024 * 1024) ? 64 : 32;
  const int chunks = 128 / Bh;
  const long R = (long)Bh * 256;

  short* Wf1 = (short*)take(1024L * 512 * 2);
  short* Wf2 = (short*)take(1024L * 1024 * 2);
  short* Wg1 = (short*)take(1024L * 1024 * 2);
  short* Wg2 = (short*)take(1024L * 1024 * 2);
  short* Wh1 = (short*)take(1024L * 2048 * 2);
  short* Wh2 = (short*)take(1024L * 1024 * 2);
  float* SUMF = (float*)take(128L * 2048 * 4);
  short* scat = (short*)take(128L * 2048 * 2);
  short* hh = (short*)take(128L * 1024 * 2);
  short* hf = (short*)take(128L * 1024 * 2);
  char* Areg = take(2 * R * 1024 * 2);  // FHID -> GHID
  char* Breg = take(2 * R * 1024 * 2);  // F12 -> CC12
  char* Creg = take(2 * R * 512 * 2);   // S12b -> E1|W1A|W2A
  char* Dreg = take(2 * R * 512 * 2);   // [S2T | S1T]
  (void)in_sizes; (void)n_in; (void)out_size;

  short* FHID = (short*)Areg;
  short* GHID = (short*)Areg;
  short* F12 = (short*)Breg;
  short* CC12 = (short*)Breg;
  short* S12b = (short*)Creg;
  float* E1 = (float*)Creg;
  short* W1A = (short*)(Creg + (long)Bh * 262144);
  short* W2A = W1A + (long)Bh * 65536;
  short* ST = (short*)Dreg;

  hipMemsetAsync(SUMF, 0, 128L * 2048 * 4, stream);

  CastArgs ca;
  ca.src[0] = f_w1; ca.dst[0] = (__hip_bfloat16*)Wf1; ca.n[0] = 524288;
  ca.src[1] = f_w2; ca.dst[1] = (__hip_bfloat16*)Wf2; ca.n[1] = 1048576;
  ca.src[2] = g_w1; ca.dst[2] = (__hip_bfloat16*)Wg1; ca.n[2] = 1048576;
  ca.src[3] = g_w2; ca.dst[3] = (__hip_bfloat16*)Wg2; ca.n[3] = 1048576;
  ca.src[4] = h_w1; ca.dst[4] = (__hip_bfloat16*)Wh1; ca.n[4] = 2097152;
  ca.src[5] = h_w2; ca.dst[5] = (__hip_bfloat16*)Wh2; ca.n[5] = 1048576;
  cast_many<<<dim3(2048, 6), 256, 0, stream>>>(ca);

  for (int c = 0; c < chunks; ++c) {
    const float* s1 = sent1 + (long)c * R * 512;
    const float* s2 = sent2 + (long)c * R * 512;
    float* SUMF_c = SUMF + (long)c * Bh * 2048;
    const int MT = (int)(2 * R / 128);

    prep_sent<<<dim3(16, 8, 2 * Bh), dim3(32, 8), 0, stream>>>(
        s1, s2, (__hip_bfloat16*)S12b, (__hip_bfloat16*)ST, Bh);

    // ---- attend MLP f (merged sides, M = 2R) ----
    gemm_nt<true, true, true, false, false><<<dim3(8, MT, 1), 256, 0, stream>>>(
        S12b, Wf1, f_b1, FHID, 512, 512, 512, 1024, 0, 0, 0, nullptr, nullptr, 0);
    gemm_nt<true, true, true, false, false><<<dim3(8, MT, 1), 256, 0, stream>>>(
        FHID, Wf2, f_b2, F12, 1024, 1024, 1024, 1024, 0, 0, 0, nullptr, nullptr, 0);

    // ---- e1 = F1 F2^T (batched fp32; overwrites S12b region) ----
    gemm_nt<false, false, false, false, false><<<dim3(2, 2, Bh), 256, 0, stream>>>(
        F12, F12 + R * 1024, nullptr, E1, 1024, 1024, 1024, 256, 256L * 1024,
        256L * 1024, 65536, nullptr, nullptr, 0);

    // ---- softmaxes ----
    softmax_rows<<<Bh * 256, 256, 0, stream>>>(E1, (__hip_bfloat16*)W1A);
    softmax_cols_f<<<dim3(4, Bh), 256, 0, stream>>>(E1, (__hip_bfloat16*)W2A);

    // ---- att (merged) + fused coalesced concat right-half fill ----
    gemm_nt<false, true, false, false, true><<<dim3(4, 2, 2 * Bh), 256, 0, stream>>>(
        W1A, ST, nullptr, CC12, 256, 256, 256, 1024, 65536, 131072, 262144,
        s1, s2, Bh);

    // ---- compare MLP g (merged); layer2 accumulates sum-over-L ----
    gemm_nt<true, true, true, false, false><<<dim3(8, MT, 1), 256, 0, stream>>>(
        CC12, Wg1, g_b1, GHID, 1024, 1024, 1024, 1024, 0, 0, 0, nullptr, nullptr, 0);
    gemm_nt<true, false, true, true, false><<<dim3(8, MT, 1), 256, 0, stream>>>(
        GHID, Wg2, g_b2, SUMF_c, 1024, 1024, 1024, 2048, 0, 0, Bh, nullptr, nullptr, 0);
  }

  // ---- aggregate MLP h + final linear ----
  cast_bf16<<<256, 256, 0, stream>>>(SUMF, (__hip_bfloat16*)scat, 262144);
  gemm_nt<true, true, true, false, false><<<dim3(8, 1, 1), 256, 0, stream>>>(
      scat, Wh1, h_b1, hh, 2048, 2048, 2048, 1024, 0, 0, 0, nullptr, nullptr, 0);
  gemm_nt<true, true, true, false, false><<<dim3(8, 1, 1), 256, 0, stream>>>(
      hh, Wh2, h_b2, hf, 1024, 1024, 1024, 1024, 0, 0, 0, nullptr, nullptr, 0);
  final_lin<<<128, 256, 0, stream>>>((__hip_bfloat16*)hf, fin_w, fin_b,
                                     (float*)d_out);
}